// Round 9
// baseline (458.566 us; speedup 1.0000x reference)
//
#include <hip/hip_runtime.h>
#include <hip/hip_bf16.h>

typedef __bf16 bf16;
typedef __bf16 bf16x8 __attribute__((ext_vector_type(8)));
typedef __bf16 bf16x4 __attribute__((ext_vector_type(4)));
typedef __bf16 bf16x2 __attribute__((ext_vector_type(2)));
typedef float  f32x4  __attribute__((ext_vector_type(4)));

#define GLD16(g, l) __builtin_amdgcn_global_load_lds(                        \
    (const __attribute__((address_space(1))) void*)(g),                      \
    (__attribute__((address_space(3))) void*)(l), 16, 0, 0)

// ---------------------------------------------------------------------------
// NT GEMM: C[m,n] = alpha * sum_k A[m,k]*B[n,k] (+ bias[n]) (+ relu) (+ res)
// BK=64; swizzled LDS (conflict-free, R2); pointer-bump staging (R3).
// Still used for the small batched W_eff GEMM only (R16).
// ---------------------------------------------------------------------------
template<int BM, int BN, int MFR, int NFR>
__global__ __launch_bounds__(256, 3)
void gemm_nt(const bf16* __restrict__ A, const bf16* __restrict__ B,
             bf16* __restrict__ C, const float* __restrict__ bias,
             int K, int lda, int ldb, int ldc,
             int inner,
             long long aOut, long long aIn,
             long long bOut, long long bIn,
             long long cOut, long long cIn,
             float alpha, int relu,
             const bf16* __restrict__ res, int ldr)
{
    const int z  = blockIdx.z;
    const int zo = z / inner;
    const int zi = z - zo * inner;
    A += (long long)zo * aOut + (long long)zi * aIn;
    B += (long long)zo * bOut + (long long)zi * bIn;
    C += (long long)zo * cOut + (long long)zi * cIn;

    const int tm = blockIdx.y * BM;
    const int tn = blockIdx.x * BN;

    __shared__ __align__(16) bf16 smem[(BM + BN) * 64];
    bf16* As = smem;
    bf16* Bs = smem + BM * 64;

    const int tid  = threadIdx.x;
    const int lane = tid & 63;
    const int wid  = tid >> 6;
    const int wr   = wid >> 1;
    const int wc   = wid & 1;

    f32x4 acc[MFR][NFR];
#pragma unroll
    for (int i = 0; i < MFR; ++i)
#pragma unroll
        for (int j = 0; j < NFR; ++j) acc[i][j] = (f32x4){0.f, 0.f, 0.f, 0.f};

    const int srow = lane >> 3;
    const int gch8 = ((lane & 7) ^ srow) * 8;

    const int NA = BM / 32;
    const int NB = BN / 32;

    const bf16* aP[NA];
#pragma unroll
    for (int jj = 0; jj < NA; ++jj) {
        const int R0 = (wid * NA + jj) * 8;
        aP[jj] = A + (long long)(tm + R0 + srow) * lda + gch8;
    }
    const bf16* bP[NB];
#pragma unroll
    for (int jj = 0; jj < NB; ++jj) {
        const int R0 = (wid * NB + jj) * 8;
        bP[jj] = B + (long long)(tn + R0 + srow) * ldb + gch8;
    }

    const int lr = lane & 15;
    const int qg = lane >> 4;

    for (int kt = 0; kt < K; kt += 64) {
#pragma unroll
        for (int jj = 0; jj < NA; ++jj)
            GLD16(aP[jj], As + (wid * NA + jj) * 512);
#pragma unroll
        for (int jj = 0; jj < NB; ++jj)
            GLD16(bP[jj], Bs + (wid * NB + jj) * 512);
        __syncthreads();

#pragma unroll
        for (int h = 0; h < 2; ++h) {
            const int off = ((qg + h * 4) ^ (lr & 7)) * 8;
            bf16x8 af[MFR], bfr[NFR];
#pragma unroll
            for (int i = 0; i < MFR; ++i)
                af[i] = *(const bf16x8*)(As + (wr * MFR * 16 + i * 16 + lr) * 64 + off);
#pragma unroll
            for (int j = 0; j < NFR; ++j)
                bfr[j] = *(const bf16x8*)(Bs + (wc * NFR * 16 + j * 16 + lr) * 64 + off);
#pragma unroll
            for (int i = 0; i < MFR; ++i)
#pragma unroll
                for (int j = 0; j < NFR; ++j)
                    acc[i][j] = __builtin_amdgcn_mfma_f32_16x16x32_bf16(
                        af[i], bfr[j], acc[i][j], 0, 0, 0);
        }
        __syncthreads();
#pragma unroll
        for (int jj = 0; jj < NA; ++jj) aP[jj] += 64;
#pragma unroll
        for (int jj = 0; jj < NB; ++jj) bP[jj] += 64;
    }

#pragma unroll
    for (int i = 0; i < MFR; ++i) {
#pragma unroll
        for (int j = 0; j < NFR; ++j) {
            const int mm0 = tm + wr * MFR * 16 + i * 16 + (lane >> 4) * 4;
            const int nn  = tn + wc * NFR * 16 + j * 16 + (lane & 15);
#pragma unroll
            for (int r = 0; r < 4; ++r) {
                float v = acc[i][j][r] * alpha;
                if (bias) v += bias[nn];
                if (res)  v += (float)res[(long long)(mm0 + r) * ldr + nn];
                if (relu) v = fmaxf(v, 0.f);
                C[(long long)(mm0 + r) * ldc + nn] = (bf16)v;
            }
        }
    }
}

// ---------------------------------------------------------------------------
// Shared GEMM fragment/staging macros (R21 flow versions, used by gemm_flow).
// ---------------------------------------------------------------------------
#define BAR8()  __builtin_amdgcn_s_barrier()

#define RD_A(S, MB)                                                          \
    _Pragma("unroll") for (int mi = 0; mi < 4; ++mi)                         \
    _Pragma("unroll") for (int h = 0; h < 2; ++h)                            \
        af[mi][h] = *(const bf16x8*)((S) + aBase + ((MB) + mi) * 1024 +      \
                                     (h ? koff1 : koff0));

#define RD_B(S, NJ)                                                          \
    _Pragma("unroll") for (int h = 0; h < 2; ++h)                            \
        bfv[NJ][h] = *(const bf16x8*)((S) + bBase + (NJ) * 1024 +            \
                                      (h ? koff1 : koff0));

#define MFMA_Q(MB, N0, N1)                                                   \
    _Pragma("unroll") for (int h = 0; h < 2; ++h)                            \
    _Pragma("unroll") for (int mi = 0; mi < 4; ++mi) {                       \
        acc[(MB)+mi][(N0)] = __builtin_amdgcn_mfma_f32_16x16x32_bf16(        \
            af[mi][h], bfv[(N0)][h], acc[(MB)+mi][(N0)], 0, 0, 0);           \
        acc[(MB)+mi][(N1)] = __builtin_amdgcn_mfma_f32_16x16x32_bf16(        \
            af[mi][h], bfv[(N1)][h], acc[(MB)+mi][(N1)], 0, 0, 0);           \
    }

// R22: setprio variant for the phase-split QKV kernel (T5: pays only on
// phase-split schedules, m218b +21-25%).
#define MFMA_QP(MB, N0, N1)                                                  \
    __builtin_amdgcn_s_setprio(1);                                           \
    MFMA_Q(MB, N0, N1)                                                       \
    __builtin_amdgcn_s_setprio(0);

#define MFMA_Q1(MB, N0)                                                      \
    _Pragma("unroll") for (int h = 0; h < 2; ++h)                            \
    _Pragma("unroll") for (int mi = 0; mi < 4; ++mi) {                       \
        acc[(MB)+mi][(N0)] = __builtin_amdgcn_mfma_f32_16x16x32_bf16(        \
            af[mi][h], bfv[(N0)][h], acc[(MB)+mi][(N0)], 0, 0, 0);           \
    }

#define STAGE_A(DST)                                                         \
    _Pragma("unroll") for (int jj = 0; jj < 4; ++jj) {                       \
        GLD16(aP[jj], (DST) + (wid * 4 + jj) * 512);  aP[jj] += 64; }

#define STAGE_B3(DST)                                                        \
    _Pragma("unroll") for (int jj = 0; jj < 3; ++jj) {                       \
        GLD16(bP[jj], (DST) + 16384 + (wid * 3 + jj) * 512);  bP[jj] += 64; }

#define END_TILE()                                                           \
    asm volatile("s_waitcnt vmcnt(0)" ::: "memory");                         \
    __builtin_amdgcn_sched_barrier(0);                                       \
    BAR8();

// R21 flow tile for BN=192 (3 n-frags/wave) — used by gemm_flow.
#define K_TILE_F3(CUR, NXT, STG, LAST)                                       \
  {                                                                          \
    RD_A((CUR), 0);                                                          \
    RD_B((CUR), 0); RD_B((CUR), 1); RD_B((CUR), 2);                          \
    if (STG) { STAGE_A(NXT) STAGE_B3(NXT) }                                  \
    MFMA_Q(0, 0, 1)                                                          \
    MFMA_Q1(0, 2)                                                            \
    RD_A((CUR), 4);                                                          \
    MFMA_Q1(4, 2)                                                            \
    MFMA_Q(4, 0, 1)                                                          \
    if (!(LAST)) { END_TILE() }                                              \
  }

// ---------------------------------------------------------------------------
// R22: QKV GEMM — spread-staged, depth-2, dead-region 4-phase schedule.
// Post-mortems R14/R19/R21 established: loads are covered, fences are
// neutral, the flow structure itself caps MfmaUtil at ~39%.  m201's lever
// (m196 A/B): SPREAD staging (2-3 loads/phase) + counted vmcnt that never
// drains.  Region lifetimes within a tile (each LDS region read once,
// retired by MFMA consumption before the phase-end barrier):
//   A-q0 (rows 0-63)    read P0 (waves wr=0) -> dead after P0 barrier
//   A-q2 (rows 128-191) read P0 (wr=1)       -> dead after P0
//   B-q0..q3            read P0+P1           -> dead after P1
//   A-q1 (64-127), A-q3 (192-255) read P2    -> dead after P2
// So tile kt stages tile kt+2 into its OWN buffer's dead regions:
//   P1: A-q0, A-q2 | P2: B-q0,B-q1,B-q2 | P3: B-q3, A-q1, A-q3.
// Staging re-mapped to 1 GLD16/thread per 64-row unit (uniform issue order
// across waves -> block-wide counted-vmcnt guarantees valid).
// ONE vmcnt(4) per tile (at tile end): everything older than the newest 4
// stages has landed -> tile kt+1 fully resident; kt+2's loads survive the
// barrier (T4: never drain in the main loop).  4 barriers/tile.
// Tiles 10/11 stage nothing; tile 10 ends with vmcnt(0) (drain, 1-tile
// cover); tile 11 has no end gate.
// ---------------------------------------------------------------------------
#define SUA(q, DST) { GLD16(aU[q], (DST) + (q) * 4096 + tid * 8);  aU[q] += 64; }
#define SUB(q, DST) { GLD16(bU[q], (DST) + 16384 + (q) * 4096 + tid * 8);  bU[q] += 64; }

#define GATE_V4() asm volatile("s_waitcnt vmcnt(4)" ::: "memory");           \
                  __builtin_amdgcn_sched_barrier(0); BAR8();
#define GATE_V0() asm volatile("s_waitcnt vmcnt(0)" ::: "memory");           \
                  __builtin_amdgcn_sched_barrier(0); BAR8();

// GMODE: 1 = vmcnt(4)+barrier (main), 2 = vmcnt(0)+barrier (tile 10),
//        0 = none (last tile)
#define K_TILE_M(S, STG, GMODE)                                              \
  {                                                                          \
    RD_A((S), 0); RD_B((S), 0); RD_B((S), 1);                                \
    MFMA_QP(0, 0, 1)                                                         \
    BAR8();                                                                  \
    RD_B((S), 2); RD_B((S), 3);                                              \
    if (STG) { SUA(0, (S)) SUA(2, (S)) }                                     \
    MFMA_QP(0, 2, 3)                                                         \
    BAR8();                                                                  \
    RD_A((S), 4);                                                            \
    if (STG) { SUB(0, (S)) SUB(1, (S)) SUB(2, (S)) }                         \
    MFMA_QP(4, 2, 3)                                                         \
    BAR8();                                                                  \
    if (STG) { SUB(3, (S)) SUA(1, (S)) SUA(3, (S)) }                         \
    MFMA_QP(4, 0, 1)                                                         \
    if ((GMODE) == 1) { GATE_V4() }                                          \
    if ((GMODE) == 2) { GATE_V0() }                                          \
  }

__global__ __launch_bounds__(512, 2)
void gemm_qkv_8ph(const bf16* __restrict__ A, const bf16* __restrict__ B,
                  bf16* __restrict__ C, const float* __restrict__ bias)
{
    constexpr int LDA = 768, LDB = 768, LDC = 3072;
    const int tm = blockIdx.y * 256;
    const int tn = blockIdx.x * 256;

    __shared__ __align__(16) bf16 smem[2][2 * 256 * 64];   // 128 KiB

    const int tid  = threadIdx.x;
    const int lane = tid & 63;
    const int wid  = tid >> 6;       // 0..7
    const int wr   = wid >> 2;       // 0..1  (m-half)
    const int wc   = wid & 3;        // 0..3  (n-quarter)
    const int lr   = lane & 15;
    const int qg   = lane >> 4;

    // unit staging: thread t stages row (q*64 + t>>3), swizzled chunk
    // (t&7)^((t>>3)&7); LDS dest = unit base + t*16B (linear; layout
    // LDS[r][c] = G[r][c ^ (r&7)] — same involution as the read side).
    const int urow = tid >> 3;                       // 0..63
    const int uch  = ((tid & 7) ^ (urow & 7)) * 8;
    const bf16* aU[4];
    const bf16* bU[4];
#pragma unroll
    for (int q = 0; q < 4; ++q) {
        aU[q] = A + (long long)(tm + q * 64 + urow) * LDA + uch;
        bU[q] = B + (long long)(tn + q * 64 + urow) * LDB + uch;
    }

    f32x4 acc[8][4];
#pragma unroll
    for (int i = 0; i < 8; ++i)
#pragma unroll
        for (int j = 0; j < 4; ++j) acc[i][j] = (f32x4){0.f, 0.f, 0.f, 0.f};

    const int aBase = (wr * 128 + lr) * 64;
    const int bBase = 16384 + (wc * 64 + lr) * 64;
    const int koff0 = ((qg    ) ^ (lr & 7)) * 8;
    const int koff1 = ((qg + 4) ^ (lr & 7)) * 8;

    bf16x8 af[4][2];
    bf16x8 bfv[4][2];

    bf16* S0 = &smem[0][0];
    bf16* S1 = &smem[1][0];

    // prologue: stage tile0 -> S0, tile1 -> S1 (8 units each); vmcnt(4)
    // retires tile0 fully (newest-4 exempt = tile1's B, gated at tile0's
    // end vmcnt(4) before tile1 reads them).
#pragma unroll
    for (int q = 0; q < 4; ++q) SUA(q, S0)
#pragma unroll
    for (int q = 0; q < 4; ++q) SUB(q, S0)
#pragma unroll
    for (int q = 0; q < 4; ++q) SUA(q, S1)
#pragma unroll
    for (int q = 0; q < 4; ++q) SUB(q, S1)
    GATE_V4()

    // 12 K-tiles: t0..t9 stage kt+2 into own buffer; t10 drains; t11 last.
#pragma unroll 1
    for (int it = 0; it < 5; ++it) {
        K_TILE_M(S0, 1, 1)
        K_TILE_M(S1, 1, 1)
    }
    K_TILE_M(S0, 0, 2)
    K_TILE_M(S1, 0, 0)

    // epilogue
    float bv[4];
#pragma unroll
    for (int j = 0; j < 4; ++j) bv[j] = bias[tn + wc * 64 + j * 16 + lr];

#pragma unroll
    for (int i = 0; i < 8; ++i) {
        const int mm0 = tm + wr * 128 + i * 16 + qg * 4;
#pragma unroll
        for (int j = 0; j < 4; ++j) {
            const int nn = tn + wc * 64 + j * 16 + lr;
#pragma unroll
            for (int r = 0; r < 4; ++r)
                C[(long long)(mm0 + r) * LDC + nn] = (bf16)(acc[i][j][r] + bv[j]);
        }
    }
}

// ---------------------------------------------------------------------------
// R16/R18/R21: flow-schedule GEMM for the three mid GEMMs (M=16384, N=768,
// K=768).  256x192 tile, grid 4x64 = 256 blocks = 100% CU fill.  (frozen)
// ---------------------------------------------------------------------------
__global__ __launch_bounds__(512, 2)
void gemm_flow(const bf16* __restrict__ A, const bf16* __restrict__ B,
               bf16* __restrict__ C, const float* __restrict__ bias,
               int lda, int ldb, int ldc, int relu,
               const bf16* __restrict__ res, int ldr)
{
    const int tm = blockIdx.y * 256;
    const int tn = blockIdx.x * 192;

    __shared__ __align__(16) bf16 smem[2][(256 + 192) * 64];   // 112 KiB

    const int tid  = threadIdx.x;
    const int lane = tid & 63;
    const int wid  = tid >> 6;       // 0..7
    const int wr   = wid >> 2;       // 0..1
    const int wc   = wid & 3;        // 0..3
    const int lr   = lane & 15;
    const int qg   = lane >> 4;

    const int srow = lane >> 3;
    const int gch8 = ((lane & 7) ^ srow) * 8;
    const bf16* aP[4];
    const bf16* bP[3];
#pragma unroll
    for (int jj = 0; jj < 4; ++jj)
        aP[jj] = A + (long long)(tm + wid * 32 + jj * 8 + srow) * lda + gch8;
#pragma unroll
    for (int jj = 0; jj < 3; ++jj)
        bP[jj] = B + (long long)(tn + wid * 24 + jj * 8 + srow) * ldb + gch8;

    f32x4 acc[8][3];
#pragma unroll
    for (int i = 0; i < 8; ++i)
#pragma unroll
        for (int j = 0; j < 3; ++j) acc[i][j] = (f32x4){0.f, 0.f, 0.f, 0.f};

    const int aBase = (wr * 128 + lr) * 64;
    const int bBase = 16384 + (wc * 48 + lr) * 64;
    const int koff0 = ((qg    ) ^ (lr & 7)) * 8;
    const int koff1 = ((qg + 4) ^ (lr & 7)) * 8;

    bf16x8 af[4][2];
    bf16x8 bfv[3][2];

    bf16* S0 = &smem[0][0];
    bf16* S1 = &smem[1][0];

    STAGE_A(S0)
    STAGE_B3(S0)
    asm volatile("s_waitcnt vmcnt(0)" ::: "memory");
    __builtin_amdgcn_sched_barrier(0);
    BAR8();

#pragma unroll 1
    for (int it = 0; it < 5; ++it) {
        K_TILE_F3(S0, S1, 1, 0)
        K_TILE_F3(S1, S0, 1, 0)
    }
    K_TILE_F3(S0, S1, 1, 0)
    K_TILE_F3(S1, S0, 0, 1)

    // epilogue: bias (+res) (+relu)
    float bv[3];
#pragma unroll
    for (int j = 0; j < 3; ++j) bv[j] = bias ? bias[tn + wc * 48 + j * 16 + lr] : 0.f;

#pragma unroll
    for (int i = 0; i < 8; ++i) {
        const int mm0 = tm + wr * 128 + i * 16 + qg * 4;
#pragma unroll
        for (int j = 0; j < 3; ++j) {
            const int nn = tn + wc * 48 + j * 16 + lr;
#pragma unroll
            for (int r = 0; r < 4; ++r) {
                float v = acc[i][j][r] + bv[j];
                if (res)  v += (float)res[(long long)(mm0 + r) * ldr + nn];
                if (relu) v = fmaxf(v, 0.f);
                C[(long long)(mm0 + r) * ldc + nn] = (bf16)v;
            }
        }
    }
}

// ---------------------------------------------------------------------------
// Fused flash-style attention (R6-verified; R13 V^T staging fused in).
// R20: R18 version.  R19's Pb-alias required a mid-tile lockstep barrier
// (cost ~10 us); R17's reg-prefetch spilled (zero VGPR headroom).  Frozen.
// ---------------------------------------------------------------------------
__global__ __launch_bounds__(256, 2)
void fused_attn_kernel(bf16* __restrict__ qkvx)
{
    const int flat = blockIdx.x;                     // 0..511
    const int qt = (flat >> 3) & 3;                  // q-tile
    const int z  = (flat & 7) | ((flat >> 5) << 3);  // b*4 + h
    const int b  = z >> 2, h = z & 3;

    const bf16* Qg = qkvx + (long long)b * 512 * 3072 + h * 192;
    const bf16* Kg = Qg + 768;
    const bf16* Vg = Qg + 1536;                      // [s][d] rows, ld 3072

    __shared__ __align__(16) bf16 Ks[64 * 192];    // [key][d], 24ch rows, XOR-swz
    __shared__ __align__(16) bf16 VTs[192 * 64];   // [d][key], 8ch rows, XOR-swz
    __shared__ __align__(16) bf16 Pb[4 * 32 * 64]; // per-wave [m][key], XOR-swz

    const int tid  = threadIdx.x;
    const int lane = tid & 63;
    const int wid  = tid >> 6;
    const int lr   = lane & 15;
    const int qg   = lane >> 4;
    const int m0   = qt * 128 + wid * 32;

    bf16x8 qf[2][6];
#pragma unroll
    for (int mt = 0; mt < 2; ++mt)
#pragma unroll
        for (int t = 0; t < 6; ++t)
            qf[mt][t] = *(const bf16x8*)(Qg + (long long)(m0 + mt * 16 + lr) * 3072
                                         + t * 32 + qg * 8);

    const bf16* kP[6];
#pragma unroll
    for (int i = 0; i < 6; ++i) {
        const int c = i * 256 + tid;
        const int krow = c / 24, kcc = c % 24;
        const int kgc  = (kcc & 24) | ((kcc & 7) ^ (krow & 7));
        kP[i] = Kg + (long long)krow * 3072 + kgc * 8;
    }
    // V transpose staging indices (fixed per thread)
    const int vkp = tid & 31;        // key pair 0..31 -> keys 2vkp, 2vkp+1
    const int vdc = tid >> 5;        // d-chunk base (+8 per i)

    f32x4 acc[2][12];
#pragma unroll
    for (int mt = 0; mt < 2; ++mt)
#pragma unroll
        for (int dt = 0; dt < 12; ++dt) acc[mt][dt] = (f32x4){0.f, 0.f, 0.f, 0.f};
    float mrow[2][4], lrow[2][4];
#pragma unroll
    for (int mt = 0; mt < 2; ++mt)
#pragma unroll
        for (int r = 0; r < 4; ++r) { mrow[mt][r] = -3e38f; lrow[mt][r] = 0.f; }

    const float alpha = 0.0721687836f;   // 1/sqrt(192)

    for (int kt = 0; kt < 8; ++kt) {
#pragma unroll
        for (int i = 0; i < 6; ++i)
            GLD16(kP[i], Ks + (i * 256 + wid * 64) * 8);
        // ---- V^T staging: 2 rows x 8 d, packed bf16x2 stores ----
#pragma unroll
        for (int i = 0; i < 3; ++i) {
            const int dc = vdc + i * 8;                  // 0..23
            const bf16* p = Vg + (long long)(2 * vkp) * 3072 + dc * 8;
            const bf16x8 v0 = *(const bf16x8*)(p);
            const bf16x8 v1 = *(const bf16x8*)(p + 3072);
#pragma unroll
            for (int j = 0; j < 8; ++j) {
                const int d = dc * 8 + j;
                bf16x2 pk; pk[0] = v0[j]; pk[1] = v1[j];
                *(bf16x2*)(VTs + d * 64 + ((vkp >> 2) ^ (d & 7)) * 8
                           + 2 * (vkp & 3)) = pk;
            }
        }
        __syncthreads();

        f32x4 sf[2][4];
#pragma unroll
        for (int mt = 0; mt < 2; ++mt)
#pragma unroll
            for (int nt = 0; nt < 4; ++nt) sf[mt][nt] = (f32x4){0.f, 0.f, 0.f, 0.f};
#pragma unroll
        for (int nt = 0; nt < 4; ++nt) {
#pragma unroll
            for (int t = 0; t < 6; ++t) {
                const int ch = t * 4 + qg;
                const int ph = (ch & 24) | ((ch & 7) ^ (lr & 7));
                const bf16x8 kf = *(const bf16x8*)(Ks + (nt * 16 + lr) * 192 + ph * 8);
                sf[0][nt] = __builtin_amdgcn_mfma_f32_16x16x32_bf16(qf[0][t], kf, sf[0][nt], 0, 0, 0);
                sf[1][nt] = __builtin_amdgcn_mfma_f32_16x16x32_bf16(qf[1][t], kf, sf[1][nt], 0, 0, 0);
            }
        }

#pragma unroll
        for (int mt = 0; mt < 2; ++mt) {
            float mx[4], a[4], rs[4], p[4][4];
#pragma unroll
            for (int r = 0; r < 4; ++r) {
                float v0 = fmaxf(sf[mt][0][r], sf[mt][1][r]);
                float v1 = fmaxf(sf[mt][2][r], sf[mt][3][r]);
                mx[r] = fmaxf(v0, v1) * alpha;
            }
#pragma unroll
            for (int msk = 1; msk <= 8; msk <<= 1)
#pragma unroll
                for (int r = 0; r < 4; ++r) mx[r] = fmaxf(mx[r], __shfl_xor(mx[r], msk));
#pragma unroll
            for (int r = 0; r < 4; ++r) {
                const float mn = fmaxf(mrow[mt][r], mx[r]);
                a[r] = __expf(mrow[mt][r] - mn);
                mrow[mt][r] = mn;
                rs[r] = 0.f;
            }
#pragma unroll
            for (int nt = 0; nt < 4; ++nt)
#pragma unroll
                for (int r = 0; r < 4; ++r) {
                    p[nt][r] = __expf(sf[mt][nt][r] * alpha - mrow[mt][r]);
                    rs[r] += p[nt][r];
                }
#pragma unroll
            for (int msk = 1; msk <= 8; msk <<= 1)
#pragma unroll
                for (int r = 0; r < 4; ++r) rs[r] += __shfl_xor(rs[r], msk);
#pragma unroll
            for (int r = 0; r < 4; ++r) lrow[mt][r] = lrow[mt][r] * a[r] + rs[r];
#pragma unroll
            for (int dt = 0; dt < 12; ++dt)
#pragma unroll
                for (int r = 0; r < 4; ++r) acc[mt][dt][r] *= a[r];
#pragma unroll
            for (int nt = 0; nt < 4; ++nt)
#pragma unroll
                for (int r = 0; r < 4; ++r) {
                    const int row = mt * 16 + qg * 4 + r;
                    const int ph2 = (nt * 2 + (lr >> 3)) ^ (row & 7);
                    Pb[wid * 2048 + row * 64 + ph2 * 8 + (lr & 7)] = (bf16)p[nt][r];
                }
        }

        bf16x8 pf[2][2];
#pragma unroll
        for (int mt = 0; mt < 2; ++mt)
#pragma unroll
            for (int ks = 0; ks < 2; ++ks) {
                const int row = mt * 16 + lr;
                const int ph  = (ks * 4 + qg) ^ (lr & 7);
                pf[mt][ks] = *(const bf16x8*)(Pb + wid * 2048 + row * 64 + ph * 8);
            }
#pragma unroll
        for (int dt = 0; dt < 12; ++dt) {
#pragma unroll
            for (int ks = 0; ks < 2; ++ks) {
                const int ph = (ks * 4 + qg) ^ (lr & 7);
                const bf16x8 vf = *(const bf16x8*)(VTs + (dt * 16 + lr) * 64 + ph * 8);
                acc[0][dt] = __builtin_amdgcn_mfma_f32_16x16x32_bf16(pf[0][ks], vf, acc[0][dt], 0, 0, 0);
                acc[1][dt] = __builtin_amdgcn_mfma_f32_16x16x32_bf16(pf[1][ks], vf, acc[1][dt], 0, 0, 0);
            }
        }
        __syncthreads();
#pragma unroll
        for (int i = 0; i < 6; ++i) kP[i] += 64 * 3072;
        Vg += 64 * 3072;
    }

    bf16* Og = qkvx + (long long)b * 512 * 3072 + h * 192;
#pragma unroll
    for (int mt = 0; mt < 2; ++mt) {
        float inv[4];
#pragma unroll
        for (int r = 0; r < 4; ++r) inv[r] = 1.0f / lrow[mt][r];
#pragma unroll
        for (int dt = 0; dt < 12; ++dt)
#pragma unroll
            for (int r = 0; r < 4; ++r) {
                const int row = m0 + mt * 16 + qg * 4 + r;
                Og[(long long)row * 3072 + dt * 16 + lr] = (bf16)(acc[mt][dt][r] * inv[r]);
            }
    }
}

// ---------------------------------------------------------------------------
// one-shot prep kernel: weight casts/transposes + fused bias + x+PE cast.
// ---------------------------------------------------------------------------
__device__ __forceinline__ void cast4(const float* src, bf16* dst, int i)
{
    const float4 v = *(const float4*)(src + (long long)i * 4);
    bf16x4 o;
    o[0] = (bf16)v.x; o[1] = (bf16)v.y; o[2] = (bf16)v.z; o[3] = (bf16)v.w;
    *(bf16x4*)(dst + (long long)i * 4) = o;
}

__global__ __launch_bounds__(256)
void prep_kernel(const float* __restrict__ wq, const float* __restrict__ wk,
                 const float* __restrict__ wv, const float* __restrict__ wx,
                 const float* __restrict__ inpw, const float* __restrict__ inpb,
                 const float* __restrict__ bq, const float* __restrict__ bk,
                 const float* __restrict__ bv, const float* __restrict__ bx,
                 const float* __restrict__ woutp, const float* __restrict__ wf1a,
                 const float* __restrict__ wf1b, const float* __restrict__ x,
                 bf16* __restrict__ WT3, bf16* __restrict__ INPJ,
                 bf16* __restrict__ WOUT, bf16* __restrict__ WF1A,
                 bf16* __restrict__ WF1B, bf16* __restrict__ WXD,
                 float* __restrict__ BCAT, bf16* __restrict__ XPE)
{
    const int blk = blockIdx.x;
    const int tid = threadIdx.x;
    __shared__ bf16 t[32][33];

    if (blk < 1728) {
        const int which = blk / 576, local = blk - which * 576;
        const float* src = (which == 0) ? wq : ((which == 1) ? wk : wv);
        bf16* dst = WT3 + (long long)which * 589824;
        const int r0 = (local / 24) * 32, c0 = (local % 24) * 32;
        const int tr = tid >> 5, tc = tid & 31;
#pragma unroll
        for (int k = 0; k < 4; ++k) {
            const int r = tr + k * 8;
            t[r][tc] = (bf16)src[(long long)(r0 + r) * 768 + c0 + tc];
        }
        __syncthreads();
#pragma unroll
        for (int k = 0; k < 4; ++k) {
            const int c = tr + k * 8;
            dst[(long long)(c0 + c) * 768 + r0 + tc] = t[tc][c];
        }
    } else if (blk < 3456) {
        cast4(inpw, INPJ, (blk - 1728) * 256 + tid);
    } else if (blk < 4032) {
        cast4(woutp, WOUT, (blk - 3456) * 256 + tid);
    } else if (blk < 4608) {
        cast4(wf1a, WF1A, (blk - 4032) * 256 + tid);
    } else if (blk < 5184) {
        cast4(wf1b, WF1B, (blk - 4608) * 256 + tid);
    } else if (blk < 5760) {
        cast4(wx, WXD, (blk - 5184) * 256 + tid);
    } else if (blk < 6051) {
        const int bl = blk - 5760;
        if (bl < 288) {
            const int g = tid >> 5, l = tid & 31;
            const int n = bl * 8 + g;
            const int zsec = n / 768;
            const float* bb = (zsec == 0) ? bq : ((zsec == 1) ? bk : bv);
            const float* wrow = inpw + (long long)n * 768;
            float s = 0.f;
            for (int d = l; d < 768; d += 32) s += wrow[d] * bb[d];
#pragma unroll
            for (int off = 16; off; off >>= 1) s += __shfl_xor(s, off);
            if (l == 0) BCAT[n] = inpb[n] + s;
        } else {
            const int n = (bl - 288) * 256 + tid;
            if (n < 768) BCAT[2304 + n] = bx[n];
        }
    } else {
        const int idx4 = ((blk - 6051) * 256 + tid) * 4;
        const int d    = idx4 % 768;
        const int row  = idx4 / 768;
        const int s    = row & 511;
        const float ksc = -0.034603417655076f;  // -2*log2(10000)/768
        const float4 xv = *(const float4*)(x + (long long)idx4);
        float a0 = (float)s * exp2f((float)d * ksc);
        float a1 = (float)s * exp2f((float)(d + 2) * ksc);
        float s0, c0, s1, c1;
        sincosf(a0, &s0, &c0);
        sincosf(a1, &s1, &c1);
        bf16x4 o;
        o[0] = (bf16)(xv.x + s0);
        o[1] = (bf16)(xv.y + c0);
        o[2] = (bf16)(xv.z + s1);
        o[3] = (bf16)(xv.w + c1);
        *(bf16x4*)(XPE + (long long)idx4) = o;
    }
}

// ---------------------------------------------------------------------------
// R19: LN1 ln2-style: 512 blocks x 256 threads, 32 rows/block, lane owns 12
// elems (24 B loads), shuffle-reduce per row.  (kept)
// ---------------------------------------------------------------------------
__global__ __launch_bounds__(256)
void ln1_kernel(const bf16* __restrict__ a, int lda_,
                bf16* __restrict__ o, int ldo,
                const float* __restrict__ g, const float* __restrict__ be)
{
    const int blk  = blockIdx.x;          // 0..511 (32 rows each)
    const int tid  = threadIdx.x;
    const int wid  = tid >> 6, lane = tid & 63;
    const int d0   = lane * 12;

    float gv[12], ev[12];
#pragma unroll
    for (int k = 0; k < 12; k += 4) {
        *(float4*)(gv + k) = *(const float4*)(g + d0 + k);
        *(float4*)(ev + k) = *(const float4*)(be + d0 + k);
    }

    for (int i = 0; i < 8; ++i) {
        const int row = blk * 32 + i * 4 + wid;
        const bf16* p = a + (long long)row * lda_ + d0;
        float xv[12];
#pragma unroll
        for (int k = 0; k < 12; k += 4) {
            const bf16x4 v = *(const bf16x4*)(p + k);
            xv[k] = (float)v[0]; xv[k+1] = (float)v[1];
            xv[k+2] = (float)v[2]; xv[k+3] = (float)v[3];
        }
        float s1 = 0.f, s2 = 0.f;
#pragma unroll
        for (int k = 0; k < 12; ++k) { s1 += xv[k]; s2 += xv[k] * xv[k]; }
        for (int off = 32; off; off >>= 1) {
            s1 += __shfl_xor(s1, off);
            s2 += __shfl_xor(s2, off);
        }
        const float mu  = s1 * (1.0f / 768.0f);
        const float var = s2 * (1.0f / 768.0f) - mu * mu;
        const float rs  = rsqrtf(var + 1e-5f);
        bf16* po = o + (long long)row * ldo + d0;
#pragma unroll
        for (int k = 0; k < 12; k += 4) {
            bf16x4 ov;
            ov[0] = (bf16)((xv[k]   - mu) * rs * gv[k]   + ev[k]);
            ov[1] = (bf16)((xv[k+1] - mu) * rs * gv[k+1] + ev[k+1]);
            ov[2] = (bf16)((xv[k+2] - mu) * rs * gv[k+2] + ev[k+2]);
            ov[3] = (bf16)((xv[k+3] - mu) * rs * gv[k+3] + ev[k+3]);
            *(bf16x4*)(po + k) = ov;
        }
    }
}

// ---------------------------------------------------------------------------
// LN2 fused with s-sum (wave-parallel, R10-verified).
// ---------------------------------------------------------------------------
__global__ __launch_bounds__(256)
void ln2_reduce_kernel(const bf16* __restrict__ src,  /* ffn+x1, ld 3072 */
                       const float* __restrict__ g, const float* __restrict__ be,
                       float* __restrict__ partial)
{
    const int blk  = blockIdx.x;          // 0..511 (32 rows each)
    const int tid  = threadIdx.x;
    const int wid  = tid >> 6, lane = tid & 63;
    const int d0   = lane * 12;

    float gv[12], ev[12];
#pragma unroll
    for (int k = 0; k < 12; k += 4) {
        *(float4*)(gv + k) = *(const float4*)(g + d0 + k);
        *(float4*)(ev + k) = *(const float4*)(be + d0 + k);
    }
    float acc[12];
#pragma unroll
    for (int k = 0; k < 12; ++k) acc[k] = 0.f;

    for (int i = 0; i < 8; ++i) {
        const int row = blk * 32 + i * 4 + wid;
        const bf16* p = src + (long long)row * 3072 + d0;
        float xv[12];
#pragma unroll
        for (int k = 0; k < 12; k += 4) {
            const bf16x4 v = *(const bf16x4*)(p + k);
            xv[k] = (float)v[0]; xv[k+1] = (float)v[1];
            xv[k+2] = (float)v[2]; xv[k+3] = (float)v[3];
        }
        float s1 = 0.f, s2 = 0.f;
#pragma unroll
        for (int k = 0; k < 12; ++k) { s1 += xv[k]; s2 += xv[k] * xv[k]; }
        for (int off = 32; off; off >>= 1) {
            s1 += __shfl_xor(s1, off);
            s2 += __shfl_xor(s2, off);
        }
        const float mu  = s1 * (1.0f / 768.0f);
        const float var = s2 * (1.0f / 768.0f) - mu * mu;
        const float rs  = rsqrtf(var + 1e-5f);
#pragma unroll
        for (int k = 0; k < 12; ++k) acc[k] += (xv[k] - mu) * rs * gv[k] + ev[k];
    }

    __shared__ float red[4][768];
#pragma unroll
    for (int k = 0; k < 12; k += 4)
        *(float4*)(&red[wid][d0 + k]) = *(const float4*)(acc + k);
    __syncthreads();
    if (wid == 0) {
#pragma unroll
        for (int k = 0; k < 12; k += 4) {
            const float4 a0 = *(const float4*)(&red[0][d0 + k]);
            const float4 a1 = *(const float4*)(&red[1][d0 + k]);
            const float4 a2 = *(const float4*)(&red[2][d0 + k]);
            const float4 a3 = *(const float4*)(&red[3][d0 + k]);
            *(float4*)(partial + (long long)blk * 768 + d0 + k) =
                make_float4(a0.x + a1.x + a2.x + a3.x, a0.y + a1.y + a2.y + a3.y,
                            a0.z + a1.z + a2.z + a3.z, a0.w + a1.w + a2.w + a3.w);
        }
    }
}

// stage 2
__global__ __launch_bounds__(192)
void reduce_fc2_stage2_kernel(const float* __restrict__ partial, const float* __restrict__ w,
                              const float* __restrict__ bias, float* __restrict__ out)
{
    const int b = blockIdx.x, t = threadIdx.x;
    const int d0 = t * 4;
    float a[4] = {0.f, 0.f, 0.f, 0.f};
    for (int c = 0; c < 16; ++c) {
        const float4 pv = *(const float4*)(partial + (long long)(b * 16 + c) * 768 + d0);
        a[0] += pv.x; a[1] += pv.y; a[2] += pv.z; a[3] += pv.w;
    }
    __shared__ float os[10];
    if (t < 10) os[t] = 0.f;
    __syncthreads();
    for (int c = 0; c < 10; ++c) {
        const float4 wv = *(const float4*)(w + c * 768 + d0);
        float p = wv.x * a[0] + wv.y * a[1] + wv.z * a[2] + wv.w * a[3];
        for (int off = 32; off; off >>= 1) p += __shfl_xor(p, off);
        if ((t & 63) == 0) atomicAdd(&os[c], p);
    }
    __syncthreads();
    if (t < 10) out[b * 10 + t] = os[t] + bias[t];
}

// ---------------------------------------------------------------------------
// workspace layout (bytes)
// ---------------------------------------------------------------------------
static const size_t OFF_XPE  = 0;
static const size_t OFF_WCAT = OFF_XPE  + (size_t)16384 * 768 * 2;
static const size_t OFF_WT3  = OFF_WCAT + (size_t)3072 * 768 * 2;
static const size_t OFF_INPJ = OFF_WT3  + (size_t)3 * 768 * 768 * 2;
static const size_t OFF_WOUT = OFF_INPJ + (size_t)2304 * 768 * 2;
static const size_t OFF_WF1A = OFF_WOUT + (size_t)768 * 768 * 2;
static const size_t OFF_WF1B = OFF_WF1A + (size_t)768 * 768 * 2;
static const size_t OFF_BCAT = OFF_WF1B + (size_t)768 * 768 * 2;
static const size_t OFF_QKVX = OFF_BCAT + (size_t)3072 * 4;
static const size_t OFF_VT   = OFF_QKVX + (size_t)16384 * 3072 * 2;   // unused (R13)
static const size_t OFF_S    = OFF_VT   + (size_t)128 * 192 * 512 * 2; // fc2 partials
static const size_t OFF_X1   = OFF_S    + (size_t)128 * 512 * 512 * 2;

extern "C" void kernel_launch(void* const* d_in, const int* in_sizes, int n_in,
                              void* d_out, int out_size, void* d_ws, size_t ws_size,
                              hipStream_t stream)
{
    const float* x     = (const float*)d_in[0];
    const float* wq    = (const float*)d_in[1];
    const float* bq    = (const float*)d_in[2];
    const float* wk    = (const float*)d_in[3];
    const float* bk    = (const float*)d_in[4];
    const float* wv    = (const float*)d_in[5];
    const float* bv    = (const float*)d_in[6];
    const float* wx    = (const float*)d_in[7];
    const float* bx    = (const float*)d_in[8];
    const float* inpw  = (const float*)d_in[9];
    const float* inpb  = (const float*)d_in[10];
    const float* woutp = (const float*)d_in[11];
    const float* boutp = (const float*)d_in[12];
    const float* wf1a  = (const float*)d_in[13];
    const float* bf1a  = (const float*)d_in[14];
    const float* wf1b  = (const float*)d_in[15];
    const float* bf1b  = (const float*)d_in[16];
    const float* lng   = (const float*)d_in[17];
    const float* lnb   = (const float*)d_in[18];
    const float* wfc2  = (const float*)d_in[19];
    const float* bfc2  = (const float*)d_in[20];
    float* out = (float*)d_out;

    char* ws = (char*)d_ws;
    bf16*  XPE  = (bf16*)(ws + OFF_XPE);
    bf16*  WCAT = (bf16*)(ws + OFF_WCAT);
    bf16*  WT3  = (bf16*)(ws + OFF_WT3);
    bf16*  INPJ = (bf16*)(ws + OFF_INPJ);
    bf16*  WOUT = (bf16*)(ws + OFF_WOUT);
    bf16*  WF1A = (bf16*)(ws + OFF_WF1A);
    bf16*  WF1B = (bf16*)(ws + OFF_WF1B);
    float* BCAT = (float*)(ws + OFF_BCAT);
    bf16*  QKVX = (bf16*)(ws + OFF_QKVX);
    float* PART = (float*)(ws + OFF_S);
    bf16*  X1   = (bf16*)(ws + OFF_X1);

    // ---- prep: weights + bias + x+PE (single dispatch) ----
    prep_kernel<<<18339, 256, 0, stream>>>(wq, wk, wv, wx, inpw, inpb,
                                           bq, bk, bv, bx, woutp, wf1a, wf1b, x,
                                           WT3, INPJ, WOUT, WF1A, WF1B,
                                           WCAT + (size_t)2304 * 768, BCAT, XPE);

    // W_eff[z] = in_proj_w[z] @ w{q,k,v}
    gemm_nt<64, 128, 2, 4><<<dim3(6, 12, 3), 256, 0, stream>>>(
        INPJ, WT3, WCAT, nullptr, 768, 768, 768, 768,
        1, 589824, 0, 589824, 0, 589824, 0, 1.0f, 0, nullptr, 0);

    // QKVX = XPE @ WCAT^T + BCAT -> [16384,3072]
    // R22: spread-staged depth-2 dead-region 4-phase schedule.
    gemm_qkv_8ph<<<dim3(12, 64, 1), 512, 0, stream>>>(XPE, WCAT, QKVX, BCAT);

    // fused attention (R18 version):
    // Q2 region overwritten with ctx
    fused_attn_kernel<<<512, 256, 0, stream>>>(QKVX);

    // attn_out + XR residual -> K2 region  (R21 flow, 256x192, 256 blocks)
    gemm_flow<<<dim3(4, 64, 1), 512, 0, stream>>>(
        QKVX, WOUT, QKVX + 768, boutp, 3072, 768, 3072,
        0, QKVX + 2304, 3072);

    // x1 = LN(attn_out + XR)  (R19: 32 rows/block)
    ln1_kernel<<<512, 256, 0, stream>>>(QKVX + 768, 3072, X1, 768, lng, lnb);

    // h1 = relu(x1 @ fc1a^T + b) -> V2 region  (R21 flow)
    gemm_flow<<<dim3(4, 64, 1), 512, 0, stream>>>(
        X1, WF1A, QKVX + 1536, bf1a, 768, 768, 3072,
        1, nullptr, 0);

    // ffn + x1 residual -> XR region  (R21 flow)
    gemm_flow<<<dim3(4, 64, 1), 512, 0, stream>>>(
        QKVX + 1536, WF1B, QKVX + 2304, bf1b, 3072, 768, 3072,
        0, X1, 768);

    // LN2 + s-sum fused (x2 never materialized)
    ln2_reduce_kernel<<<512, 256, 0, stream>>>(QKVX + 2304, lng, lnb, PART);

    // out = partial-sum @ fc2^T + b
    reduce_fc2_stage2_kernel<<<32, 192, 0, stream>>>(PART, wfc2, bfc2, out);
}

// Round 10
// 442.938 us; speedup vs baseline: 1.0353x; 1.0353x over previous
//
#include <hip/hip_runtime.h>
#include <hip/hip_bf16.h>

typedef __bf16 bf16;
typedef __bf16 bf16x8 __attribute__((ext_vector_type(8)));
typedef __bf16 bf16x4 __attribute__((ext_vector_type(4)));
typedef __bf16 bf16x2 __attribute__((ext_vector_type(2)));
typedef float  f32x4  __attribute__((ext_vector_type(4)));

#define GLD16(g, l) __builtin_amdgcn_global_load_lds(                        \
    (const __attribute__((address_space(1))) void*)(g),                      \
    (__attribute__((address_space(3))) void*)(l), 16, 0, 0)

// ---------------------------------------------------------------------------
// NT GEMM: C[m,n] = alpha * sum_k A[m,k]*B[n,k] (+ bias[n]) (+ relu) (+ res)
// BK=64; swizzled LDS (conflict-free, R2); pointer-bump staging (R3).
// Still used for the small batched W_eff GEMM only (R16).
// ---------------------------------------------------------------------------
template<int BM, int BN, int MFR, int NFR>
__global__ __launch_bounds__(256, 3)
void gemm_nt(const bf16* __restrict__ A, const bf16* __restrict__ B,
             bf16* __restrict__ C, const float* __restrict__ bias,
             int K, int lda, int ldb, int ldc,
             int inner,
             long long aOut, long long aIn,
             long long bOut, long long bIn,
             long long cOut, long long cIn,
             float alpha, int relu,
             const bf16* __restrict__ res, int ldr)
{
    const int z  = blockIdx.z;
    const int zo = z / inner;
    const int zi = z - zo * inner;
    A += (long long)zo * aOut + (long long)zi * aIn;
    B += (long long)zo * bOut + (long long)zi * bIn;
    C += (long long)zo * cOut + (long long)zi * cIn;

    const int tm = blockIdx.y * BM;
    const int tn = blockIdx.x * BN;

    __shared__ __align__(16) bf16 smem[(BM + BN) * 64];
    bf16* As = smem;
    bf16* Bs = smem + BM * 64;

    const int tid  = threadIdx.x;
    const int lane = tid & 63;
    const int wid  = tid >> 6;
    const int wr   = wid >> 1;
    const int wc   = wid & 1;

    f32x4 acc[MFR][NFR];
#pragma unroll
    for (int i = 0; i < MFR; ++i)
#pragma unroll
        for (int j = 0; j < NFR; ++j) acc[i][j] = (f32x4){0.f, 0.f, 0.f, 0.f};

    const int srow = lane >> 3;
    const int gch8 = ((lane & 7) ^ srow) * 8;

    const int NA = BM / 32;
    const int NB = BN / 32;

    const bf16* aP[NA];
#pragma unroll
    for (int jj = 0; jj < NA; ++jj) {
        const int R0 = (wid * NA + jj) * 8;
        aP[jj] = A + (long long)(tm + R0 + srow) * lda + gch8;
    }
    const bf16* bP[NB];
#pragma unroll
    for (int jj = 0; jj < NB; ++jj) {
        const int R0 = (wid * NB + jj) * 8;
        bP[jj] = B + (long long)(tn + R0 + srow) * ldb + gch8;
    }

    const int lr = lane & 15;
    const int qg = lane >> 4;

    for (int kt = 0; kt < K; kt += 64) {
#pragma unroll
        for (int jj = 0; jj < NA; ++jj)
            GLD16(aP[jj], As + (wid * NA + jj) * 512);
#pragma unroll
        for (int jj = 0; jj < NB; ++jj)
            GLD16(bP[jj], Bs + (wid * NB + jj) * 512);
        __syncthreads();

#pragma unroll
        for (int h = 0; h < 2; ++h) {
            const int off = ((qg + h * 4) ^ (lr & 7)) * 8;
            bf16x8 af[MFR], bfr[NFR];
#pragma unroll
            for (int i = 0; i < MFR; ++i)
                af[i] = *(const bf16x8*)(As + (wr * MFR * 16 + i * 16 + lr) * 64 + off);
#pragma unroll
            for (int j = 0; j < NFR; ++j)
                bfr[j] = *(const bf16x8*)(Bs + (wc * NFR * 16 + j * 16 + lr) * 64 + off);
#pragma unroll
            for (int i = 0; i < MFR; ++i)
#pragma unroll
                for (int j = 0; j < NFR; ++j)
                    acc[i][j] = __builtin_amdgcn_mfma_f32_16x16x32_bf16(
                        af[i], bfr[j], acc[i][j], 0, 0, 0);
        }
        __syncthreads();
#pragma unroll
        for (int jj = 0; jj < NA; ++jj) aP[jj] += 64;
#pragma unroll
        for (int jj = 0; jj < NB; ++jj) bP[jj] += 64;
    }

#pragma unroll
    for (int i = 0; i < MFR; ++i) {
#pragma unroll
        for (int j = 0; j < NFR; ++j) {
            const int mm0 = tm + wr * MFR * 16 + i * 16 + (lane >> 4) * 4;
            const int nn  = tn + wc * NFR * 16 + j * 16 + (lane & 15);
#pragma unroll
            for (int r = 0; r < 4; ++r) {
                float v = acc[i][j][r] * alpha;
                if (bias) v += bias[nn];
                if (res)  v += (float)res[(long long)(mm0 + r) * ldr + nn];
                if (relu) v = fmaxf(v, 0.f);
                C[(long long)(mm0 + r) * ldc + nn] = (bf16)v;
            }
        }
    }
}

// ---------------------------------------------------------------------------
// R23: QKV + mids REVERTED to the R15/R18-measured fenced flow schedule.
// Schedule-search post-mortems: R15-fenced = 82.5-83.6 us (3 healthy runs,
// MfmaUtil 39-40); R21-unfenced = 87; R22 depth-2 convoy = 88.5 (null per
// pre-commit).  The ~40%-util flow plateau stands; QKV experiments closed.
// ---------------------------------------------------------------------------
#define BAR8()  __builtin_amdgcn_s_barrier()
#define LGKM0() do { asm volatile("s_waitcnt lgkmcnt(0)" ::: "memory");      \
                     __builtin_amdgcn_sched_barrier(0); } while (0)

#define RD_A(S, MB)                                                          \
    _Pragma("unroll") for (int mi = 0; mi < 4; ++mi)                         \
    _Pragma("unroll") for (int h = 0; h < 2; ++h)                            \
        af[mi][h] = *(const bf16x8*)((S) + aBase + ((MB) + mi) * 1024 +      \
                                     (h ? koff1 : koff0));

#define RD_B(S, NJ)                                                          \
    _Pragma("unroll") for (int h = 0; h < 2; ++h)                            \
        bfv[NJ][h] = *(const bf16x8*)((S) + bBase + (NJ) * 1024 +            \
                                      (h ? koff1 : koff0));

#define MFMA_Q(MB, N0, N1)                                                   \
    __builtin_amdgcn_s_setprio(1);                                          \
    _Pragma("unroll") for (int h = 0; h < 2; ++h)                            \
    _Pragma("unroll") for (int mi = 0; mi < 4; ++mi) {                       \
        acc[(MB)+mi][(N0)] = __builtin_amdgcn_mfma_f32_16x16x32_bf16(        \
            af[mi][h], bfv[(N0)][h], acc[(MB)+mi][(N0)], 0, 0, 0);           \
        acc[(MB)+mi][(N1)] = __builtin_amdgcn_mfma_f32_16x16x32_bf16(        \
            af[mi][h], bfv[(N1)][h], acc[(MB)+mi][(N1)], 0, 0, 0);           \
    }                                                                        \
    __builtin_amdgcn_s_setprio(0);

#define MFMA_Q1(MB, N0)                                                      \
    __builtin_amdgcn_s_setprio(1);                                          \
    _Pragma("unroll") for (int h = 0; h < 2; ++h)                            \
    _Pragma("unroll") for (int mi = 0; mi < 4; ++mi) {                       \
        acc[(MB)+mi][(N0)] = __builtin_amdgcn_mfma_f32_16x16x32_bf16(        \
            af[mi][h], bfv[(N0)][h], acc[(MB)+mi][(N0)], 0, 0, 0);           \
    }                                                                        \
    __builtin_amdgcn_s_setprio(0);

#define STAGE_A(DST)                                                         \
    _Pragma("unroll") for (int jj = 0; jj < 4; ++jj) {                       \
        GLD16(aP[jj], (DST) + (wid * 4 + jj) * 512);  aP[jj] += 64; }

#define STAGE_B(DST)                                                         \
    _Pragma("unroll") for (int jj = 0; jj < 4; ++jj) {                       \
        GLD16(bP[jj], (DST) + 16384 + (wid * 4 + jj) * 512);  bP[jj] += 64; }

#define STAGE_B3(DST)                                                        \
    _Pragma("unroll") for (int jj = 0; jj < 3; ++jj) {                       \
        GLD16(bP[jj], (DST) + 16384 + (wid * 3 + jj) * 512);  bP[jj] += 64; }

#define K_TILE_F(CUR, NXT, STG, LAST)                                        \
  {                                                                          \
    RD_A((CUR), 0); RD_B((CUR), 0); RD_B((CUR), 1);                          \
    if (STG) { STAGE_A(NXT) }                                                \
    LGKM0();                                                                 \
    MFMA_Q(0, 0, 1)                                                          \
    RD_B((CUR), 2); RD_B((CUR), 3);                                          \
    if (STG) { STAGE_B(NXT) }                                                \
    LGKM0();                                                                 \
    MFMA_Q(0, 2, 3)                                                          \
    RD_A((CUR), 4);                                                          \
    LGKM0();                                                                 \
    MFMA_Q(4, 2, 3)                                                          \
    MFMA_Q(4, 0, 1)                                                          \
    if (!(LAST)) { asm volatile("s_waitcnt vmcnt(0)" ::: "memory");          \
                   __builtin_amdgcn_sched_barrier(0); BAR8(); }              \
  }

// BN=192 variant (3 n-frags/wave), B staged with 3 GLD16/thread.
#define K_TILE_F3(CUR, NXT, STG, LAST)                                       \
  {                                                                          \
    RD_A((CUR), 0); RD_B((CUR), 0); RD_B((CUR), 1);                          \
    if (STG) { STAGE_A(NXT) }                                                \
    LGKM0();                                                                 \
    MFMA_Q(0, 0, 1)                                                          \
    RD_B((CUR), 2);                                                          \
    if (STG) { STAGE_B3(NXT) }                                               \
    LGKM0();                                                                 \
    MFMA_Q1(0, 2)                                                            \
    RD_A((CUR), 4);                                                          \
    LGKM0();                                                                 \
    MFMA_Q1(4, 2)                                                            \
    MFMA_Q(4, 0, 1)                                                          \
    if (!(LAST)) { asm volatile("s_waitcnt vmcnt(0)" ::: "memory");          \
                   __builtin_amdgcn_sched_barrier(0); BAR8(); }              \
  }

__global__ __launch_bounds__(512, 2)
void gemm_qkv_8ph(const bf16* __restrict__ A, const bf16* __restrict__ B,
                  bf16* __restrict__ C, const float* __restrict__ bias)
{
    constexpr int LDA = 768, LDB = 768, LDC = 3072;
    const int tm = blockIdx.y * 256;
    const int tn = blockIdx.x * 256;

    __shared__ __align__(16) bf16 smem[2][2 * 256 * 64];   // 128 KiB

    const int tid  = threadIdx.x;
    const int lane = tid & 63;
    const int wid  = tid >> 6;       // 0..7
    const int wr   = wid >> 2;       // 0..1  (m-half of block tile)
    const int wc   = wid & 3;        // 0..3  (n-quarter)
    const int lr   = lane & 15;
    const int qg   = lane >> 4;

    // staging (pre-swizzled global source, linear LDS dest: LDS[row][c] =
    // G[row][c ^ (row&7)])
    const int srow = lane >> 3;
    const int gch8 = ((lane & 7) ^ srow) * 8;
    const bf16* aP[4];
    const bf16* bP[4];
#pragma unroll
    for (int jj = 0; jj < 4; ++jj) {
        aP[jj] = A + (long long)(tm + wid * 32 + jj * 8 + srow) * LDA + gch8;
        bP[jj] = B + (long long)(tn + wid * 32 + jj * 8 + srow) * LDB + gch8;
    }

    f32x4 acc[8][4];
#pragma unroll
    for (int i = 0; i < 8; ++i)
#pragma unroll
        for (int j = 0; j < 4; ++j) acc[i][j] = (f32x4){0.f, 0.f, 0.f, 0.f};

    const int aBase = (wr * 128 + lr) * 64;
    const int bBase = 16384 + (wc * 64 + lr) * 64;
    const int koff0 = ((qg    ) ^ (lr & 7)) * 8;
    const int koff1 = ((qg + 4) ^ (lr & 7)) * 8;

    bf16x8 af[4][2];     // current A m-half (lo in bursts 0-1, hi in burst 2)
    bf16x8 bfv[4][2];    // all 4 B n-frags live across the K-tile

    bf16* S0 = &smem[0][0];
    bf16* S1 = &smem[1][0];

    // prologue: stage tile 0 into S0, drain, converge
    STAGE_A(S0)
    STAGE_B(S0)
    asm volatile("s_waitcnt vmcnt(0)" ::: "memory");
    BAR8();

    // K = 768 -> 12 K-tiles.  Tiles 0..10 stage tile kt+1 into the other
    // buffer; tile 11 computes only.
#pragma unroll 1
    for (int it = 0; it < 5; ++it) {
        K_TILE_F(S0, S1, 1, 0)
        K_TILE_F(S1, S0, 1, 0)
    }
    K_TILE_F(S0, S1, 1, 0)
    K_TILE_F(S1, S0, 0, 1)

    // epilogue
    float bv[4];
#pragma unroll
    for (int j = 0; j < 4; ++j) bv[j] = bias[tn + wc * 64 + j * 16 + lr];

#pragma unroll
    for (int i = 0; i < 8; ++i) {
        const int mm0 = tm + wr * 128 + i * 16 + qg * 4;
#pragma unroll
        for (int j = 0; j < 4; ++j) {
            const int nn = tn + wc * 64 + j * 16 + lr;
#pragma unroll
            for (int r = 0; r < 4; ++r)
                C[(long long)(mm0 + r) * LDC + nn] = (bf16)(acc[i][j][r] + bv[j]);
        }
    }
}

// ---------------------------------------------------------------------------
// R16/R18/R23: flow-schedule GEMM for the three mid GEMMs (M=16384, N=768,
// K=768).  256x192 tile, 256 blocks = 100% CU fill.
// R23: GRID SWAPPED to dim3(64,4): tm <- blockIdx.x, tn <- blockIdx.y.
// Mechanism (T1 applied to the A-panel): the 4 n-tile blocks sharing A-panel
// x are flats {x, 64+x, 128+x, 192+x} -> XCD x%8 for ALL FOUR (64 % 8 == 0),
// so A (25 MB, ld-3072 strided, the dominant operand) is fetched once into
// that XCD's L2 and reused 3x, instead of 4 fetches from 4 different XCDs.
// B (1.2 MB) is L2-resident everywhere regardless.
// ---------------------------------------------------------------------------
__global__ __launch_bounds__(512, 2)
void gemm_flow(const bf16* __restrict__ A, const bf16* __restrict__ B,
               bf16* __restrict__ C, const float* __restrict__ bias,
               int lda, int ldb, int ldc, int relu,
               const bf16* __restrict__ res, int ldr)
{
    const int tm = blockIdx.x * 256;    // R23: m-tile on x (fastest)
    const int tn = blockIdx.y * 192;    // R23: n-tile on y

    __shared__ __align__(16) bf16 smem[2][(256 + 192) * 64];   // 112 KiB

    const int tid  = threadIdx.x;
    const int lane = tid & 63;
    const int wid  = tid >> 6;       // 0..7
    const int wr   = wid >> 2;       // 0..1
    const int wc   = wid & 3;        // 0..3
    const int lr   = lane & 15;
    const int qg   = lane >> 4;

    const int srow = lane >> 3;
    const int gch8 = ((lane & 7) ^ srow) * 8;
    const bf16* aP[4];
    const bf16* bP[3];
#pragma unroll
    for (int jj = 0; jj < 4; ++jj)
        aP[jj] = A + (long long)(tm + wid * 32 + jj * 8 + srow) * lda + gch8;
#pragma unroll
    for (int jj = 0; jj < 3; ++jj)
        bP[jj] = B + (long long)(tn + wid * 24 + jj * 8 + srow) * ldb + gch8;

    f32x4 acc[8][3];
#pragma unroll
    for (int i = 0; i < 8; ++i)
#pragma unroll
        for (int j = 0; j < 3; ++j) acc[i][j] = (f32x4){0.f, 0.f, 0.f, 0.f};

    const int aBase = (wr * 128 + lr) * 64;
    const int bBase = 16384 + (wc * 48 + lr) * 64;
    const int koff0 = ((qg    ) ^ (lr & 7)) * 8;
    const int koff1 = ((qg + 4) ^ (lr & 7)) * 8;

    bf16x8 af[4][2];
    bf16x8 bfv[3][2];

    bf16* S0 = &smem[0][0];
    bf16* S1 = &smem[1][0];

    STAGE_A(S0)
    STAGE_B3(S0)
    asm volatile("s_waitcnt vmcnt(0)" ::: "memory");
    BAR8();

#pragma unroll 1
    for (int it = 0; it < 5; ++it) {
        K_TILE_F3(S0, S1, 1, 0)
        K_TILE_F3(S1, S0, 1, 0)
    }
    K_TILE_F3(S0, S1, 1, 0)
    K_TILE_F3(S1, S0, 0, 1)

    // epilogue: bias (+res) (+relu)
    float bv[3];
#pragma unroll
    for (int j = 0; j < 3; ++j) bv[j] = bias ? bias[tn + wc * 48 + j * 16 + lr] : 0.f;

#pragma unroll
    for (int i = 0; i < 8; ++i) {
        const int mm0 = tm + wr * 128 + i * 16 + qg * 4;
#pragma unroll
        for (int j = 0; j < 3; ++j) {
            const int nn = tn + wc * 48 + j * 16 + lr;
#pragma unroll
            for (int r = 0; r < 4; ++r) {
                float v = acc[i][j][r] + bv[j];
                if (res)  v += (float)res[(long long)(mm0 + r) * ldr + nn];
                if (relu) v = fmaxf(v, 0.f);
                C[(long long)(mm0 + r) * ldc + nn] = (bf16)v;
            }
        }
    }
}

// ---------------------------------------------------------------------------
// Fused flash-style attention (R6-verified; R13 V^T staging fused in).
// R20: R18 version.  R19's Pb-alias required a mid-tile lockstep barrier
// (cost ~10 us); R17's reg-prefetch spilled (zero VGPR headroom).  Frozen.
// ---------------------------------------------------------------------------
__global__ __launch_bounds__(256, 2)
void fused_attn_kernel(bf16* __restrict__ qkvx)
{
    const int flat = blockIdx.x;                     // 0..511
    const int qt = (flat >> 3) & 3;                  // q-tile
    const int z  = (flat & 7) | ((flat >> 5) << 3);  // b*4 + h
    const int b  = z >> 2, h = z & 3;

    const bf16* Qg = qkvx + (long long)b * 512 * 3072 + h * 192;
    const bf16* Kg = Qg + 768;
    const bf16* Vg = Qg + 1536;                      // [s][d] rows, ld 3072

    __shared__ __align__(16) bf16 Ks[64 * 192];    // [key][d], 24ch rows, XOR-swz
    __shared__ __align__(16) bf16 VTs[192 * 64];   // [d][key], 8ch rows, XOR-swz
    __shared__ __align__(16) bf16 Pb[4 * 32 * 64]; // per-wave [m][key], XOR-swz

    const int tid  = threadIdx.x;
    const int lane = tid & 63;
    const int wid  = tid >> 6;
    const int lr   = lane & 15;
    const int qg   = lane >> 4;
    const int m0   = qt * 128 + wid * 32;

    bf16x8 qf[2][6];
#pragma unroll
    for (int mt = 0; mt < 2; ++mt)
#pragma unroll
        for (int t = 0; t < 6; ++t)
            qf[mt][t] = *(const bf16x8*)(Qg + (long long)(m0 + mt * 16 + lr) * 3072
                                         + t * 32 + qg * 8);

    const bf16* kP[6];
#pragma unroll
    for (int i = 0; i < 6; ++i) {
        const int c = i * 256 + tid;
        const int krow = c / 24, kcc = c % 24;
        const int kgc  = (kcc & 24) | ((kcc & 7) ^ (krow & 7));
        kP[i] = Kg + (long long)krow * 3072 + kgc * 8;
    }
    // V transpose staging indices (fixed per thread)
    const int vkp = tid & 31;        // key pair 0..31 -> keys 2vkp, 2vkp+1
    const int vdc = tid >> 5;        // d-chunk base (+8 per i)

    f32x4 acc[2][12];
#pragma unroll
    for (int mt = 0; mt < 2; ++mt)
#pragma unroll
        for (int dt = 0; dt < 12; ++dt) acc[mt][dt] = (f32x4){0.f, 0.f, 0.f, 0.f};
    float mrow[2][4], lrow[2][4];
#pragma unroll
    for (int mt = 0; mt < 2; ++mt)
#pragma unroll
        for (int r = 0; r < 4; ++r) { mrow[mt][r] = -3e38f; lrow[mt][r] = 0.f; }

    const float alpha = 0.0721687836f;   // 1/sqrt(192)

    for (int kt = 0; kt < 8; ++kt) {
#pragma unroll
        for (int i = 0; i < 6; ++i)
            GLD16(kP[i], Ks + (i * 256 + wid * 64) * 8);
        // ---- V^T staging: 2 rows x 8 d, packed bf16x2 stores ----
#pragma unroll
        for (int i = 0; i < 3; ++i) {
            const int dc = vdc + i * 8;                  // 0..23
            const bf16* p = Vg + (long long)(2 * vkp) * 3072 + dc * 8;
            const bf16x8 v0 = *(const bf16x8*)(p);
            const bf16x8 v1 = *(const bf16x8*)(p + 3072);
#pragma unroll
            for (int j = 0; j < 8; ++j) {
                const int d = dc * 8 + j;
                bf16x2 pk; pk[0] = v0[j]; pk[1] = v1[j];
                *(bf16x2*)(VTs + d * 64 + ((vkp >> 2) ^ (d & 7)) * 8
                           + 2 * (vkp & 3)) = pk;
            }
        }
        __syncthreads();

        f32x4 sf[2][4];
#pragma unroll
        for (int mt = 0; mt < 2; ++mt)
#pragma unroll
            for (int nt = 0; nt < 4; ++nt) sf[mt][nt] = (f32x4){0.f, 0.f, 0.f, 0.f};
#pragma unroll
        for (int nt = 0; nt < 4; ++nt) {
#pragma unroll
            for (int t = 0; t < 6; ++t) {
                const int ch = t * 4 + qg;
                const int ph = (ch & 24) | ((ch & 7) ^ (lr & 7));
                const bf16x8 kf = *(const bf16x8*)(Ks + (nt * 16 + lr) * 192 + ph * 8);
                sf[0][nt] = __builtin_amdgcn_mfma_f32_16x16x32_bf16(qf[0][t], kf, sf[0][nt], 0, 0, 0);
                sf[1][nt] = __builtin_amdgcn_mfma_f32_16x16x32_bf16(qf[1][t], kf, sf[1][nt], 0, 0, 0);
            }
        }

#pragma unroll
        for (int mt = 0; mt < 2; ++mt) {
            float mx[4], a[4], rs[4], p[4][4];
#pragma unroll
            for (int r = 0; r < 4; ++r) {
                float v0 = fmaxf(sf[mt][0][r], sf[mt][1][r]);
                float v1 = fmaxf(sf[mt][2][r], sf[mt][3][r]);
                mx[r] = fmaxf(v0, v1) * alpha;
            }
#pragma unroll
            for (int msk = 1; msk <= 8; msk <<= 1)
#pragma unroll
                for (int r = 0; r < 4; ++r) mx[r] = fmaxf(mx[r], __shfl_xor(mx[r], msk));
#pragma unroll
            for (int r = 0; r < 4; ++r) {
                const float mn = fmaxf(mrow[mt][r], mx[r]);
                a[r] = __expf(mrow[mt][r] - mn);
                mrow[mt][r] = mn;
                rs[r] = 0.f;
            }
#pragma unroll
            for (int nt = 0; nt < 4; ++nt)
#pragma unroll
                for (int r = 0; r < 4; ++r) {
                    p[nt][r] = __expf(sf[mt][nt][r] * alpha - mrow[mt][r]);
                    rs[r] += p[nt][r];
                }
#pragma unroll
            for (int msk = 1; msk <= 8; msk <<= 1)
#pragma unroll
                for (int r = 0; r < 4; ++r) rs[r] += __shfl_xor(rs[r], msk);
#pragma unroll
            for (int r = 0; r < 4; ++r) lrow[mt][r] = lrow[mt][r] * a[r] + rs[r];
#pragma unroll
            for (int dt = 0; dt < 12; ++dt)
#pragma unroll
                for (int r = 0; r < 4; ++r) acc[mt][dt][r] *= a[r];
#pragma unroll
            for (int nt = 0; nt < 4; ++nt)
#pragma unroll
                for (int r = 0; r < 4; ++r) {
                    const int row = mt * 16 + qg * 4 + r;
                    const int ph2 = (nt * 2 + (lr >> 3)) ^ (row & 7);
                    Pb[wid * 2048 + row * 64 + ph2 * 8 + (lr & 7)] = (bf16)p[nt][r];
                }
        }

        bf16x8 pf[2][2];
#pragma unroll
        for (int mt = 0; mt < 2; ++mt)
#pragma unroll
            for (int ks = 0; ks < 2; ++ks) {
                const int row = mt * 16 + lr;
                const int ph  = (ks * 4 + qg) ^ (lr & 7);
                pf[mt][ks] = *(const bf16x8*)(Pb + wid * 2048 + row * 64 + ph * 8);
            }
#pragma unroll
        for (int dt = 0; dt < 12; ++dt) {
#pragma unroll
            for (int ks = 0; ks < 2; ++ks) {
                const int ph = (ks * 4 + qg) ^ (lr & 7);
                const bf16x8 vf = *(const bf16x8*)(VTs + (dt * 16 + lr) * 64 + ph * 8);
                acc[0][dt] = __builtin_amdgcn_mfma_f32_16x16x32_bf16(pf[0][ks], vf, acc[0][dt], 0, 0, 0);
                acc[1][dt] = __builtin_amdgcn_mfma_f32_16x16x32_bf16(pf[1][ks], vf, acc[1][dt], 0, 0, 0);
            }
        }
        __syncthreads();
#pragma unroll
        for (int i = 0; i < 6; ++i) kP[i] += 64 * 3072;
        Vg += 64 * 3072;
    }

    bf16* Og = qkvx + (long long)b * 512 * 3072 + h * 192;
#pragma unroll
    for (int mt = 0; mt < 2; ++mt) {
        float inv[4];
#pragma unroll
        for (int r = 0; r < 4; ++r) inv[r] = 1.0f / lrow[mt][r];
#pragma unroll
        for (int dt = 0; dt < 12; ++dt)
#pragma unroll
            for (int r = 0; r < 4; ++r) {
                const int row = m0 + mt * 16 + qg * 4 + r;
                Og[(long long)row * 3072 + dt * 16 + lr] = (bf16)(acc[mt][dt][r] * inv[r]);
            }
    }
}

// ---------------------------------------------------------------------------
// one-shot prep kernel: weight casts/transposes + fused bias + x+PE cast.
// ---------------------------------------------------------------------------
__device__ __forceinline__ void cast4(const float* src, bf16* dst, int i)
{
    const float4 v = *(const float4*)(src + (long long)i * 4);
    bf16x4 o;
    o[0] = (bf16)v.x; o[1] = (bf16)v.y; o[2] = (bf16)v.z; o[3] = (bf16)v.w;
    *(bf16x4*)(dst + (long long)i * 4) = o;
}

__global__ __launch_bounds__(256)
void prep_kernel(const float* __restrict__ wq, const float* __restrict__ wk,
                 const float* __restrict__ wv, const float* __restrict__ wx,
                 const float* __restrict__ inpw, const float* __restrict__ inpb,
                 const float* __restrict__ bq, const float* __restrict__ bk,
                 const float* __restrict__ bv, const float* __restrict__ bx,
                 const float* __restrict__ woutp, const float* __restrict__ wf1a,
                 const float* __restrict__ wf1b, const float* __restrict__ x,
                 bf16* __restrict__ WT3, bf16* __restrict__ INPJ,
                 bf16* __restrict__ WOUT, bf16* __restrict__ WF1A,
                 bf16* __restrict__ WF1B, bf16* __restrict__ WXD,
                 float* __restrict__ BCAT, bf16* __restrict__ XPE)
{
    const int blk = blockIdx.x;
    const int tid = threadIdx.x;
    __shared__ bf16 t[32][33];

    if (blk < 1728) {
        const int which = blk / 576, local = blk - which * 576;
        const float* src = (which == 0) ? wq : ((which == 1) ? wk : wv);
        bf16* dst = WT3 + (long long)which * 589824;
        const int r0 = (local / 24) * 32, c0 = (local % 24) * 32;
        const int tr = tid >> 5, tc = tid & 31;
#pragma unroll
        for (int k = 0; k < 4; ++k) {
            const int r = tr + k * 8;
            t[r][tc] = (bf16)src[(long long)(r0 + r) * 768 + c0 + tc];
        }
        __syncthreads();
#pragma unroll
        for (int k = 0; k < 4; ++k) {
            const int c = tr + k * 8;
            dst[(long long)(c0 + c) * 768 + r0 + tc] = t[tc][c];
        }
    } else if (blk < 3456) {
        cast4(inpw, INPJ, (blk - 1728) * 256 + tid);
    } else if (blk < 4032) {
        cast4(woutp, WOUT, (blk - 3456) * 256 + tid);
    } else if (blk < 4608) {
        cast4(wf1a, WF1A, (blk - 4032) * 256 + tid);
    } else if (blk < 5184) {
        cast4(wf1b, WF1B, (blk - 4608) * 256 + tid);
    } else if (blk < 5760) {
        cast4(wx, WXD, (blk - 5184) * 256 + tid);
    } else if (blk < 6051) {
        const int bl = blk - 5760;
        if (bl < 288) {
            const int g = tid >> 5, l = tid & 31;
            const int n = bl * 8 + g;
            const int zsec = n / 768;
            const float* bb = (zsec == 0) ? bq : ((zsec == 1) ? bk : bv);
            const float* wrow = inpw + (long long)n * 768;
            float s = 0.f;
            for (int d = l; d < 768; d += 32) s += wrow[d] * bb[d];
#pragma unroll
            for (int off = 16; off; off >>= 1) s += __shfl_xor(s, off);
            if (l == 0) BCAT[n] = inpb[n] + s;
        } else {
            const int n = (bl - 288) * 256 + tid;
            if (n < 768) BCAT[2304 + n] = bx[n];
        }
    } else {
        const int idx4 = ((blk - 6051) * 256 + tid) * 4;
        const int d    = idx4 % 768;
        const int row  = idx4 / 768;
        const int s    = row & 511;
        const float ksc = -0.034603417655076f;  // -2*log2(10000)/768
        const float4 xv = *(const float4*)(x + (long long)idx4);
        float a0 = (float)s * exp2f((float)d * ksc);
        float a1 = (float)s * exp2f((float)(d + 2) * ksc);
        float s0, c0, s1, c1;
        sincosf(a0, &s0, &c0);
        sincosf(a1, &s1, &c1);
        bf16x4 o;
        o[0] = (bf16)(xv.x + s0);
        o[1] = (bf16)(xv.y + c0);
        o[2] = (bf16)(xv.z + s1);
        o[3] = (bf16)(xv.w + c1);
        *(bf16x4*)(XPE + (long long)idx4) = o;
    }
}

// ---------------------------------------------------------------------------
// R19: LN1 ln2-style: 512 blocks x 256 threads, 32 rows/block, lane owns 12
// elems (24 B loads), shuffle-reduce per row.  (kept)
// ---------------------------------------------------------------------------
__global__ __launch_bounds__(256)
void ln1_kernel(const bf16* __restrict__ a, int lda_,
                bf16* __restrict__ o, int ldo,
                const float* __restrict__ g, const float* __restrict__ be)
{
    const int blk  = blockIdx.x;          // 0..511 (32 rows each)
    const int tid  = threadIdx.x;
    const int wid  = tid >> 6, lane = tid & 63;
    const int d0   = lane * 12;

    float gv[12], ev[12];
#pragma unroll
    for (int k = 0; k < 12; k += 4) {
        *(float4*)(gv + k) = *(const float4*)(g + d0 + k);
        *(float4*)(ev + k) = *(const float4*)(be + d0 + k);
    }

    for (int i = 0; i < 8; ++i) {
        const int row = blk * 32 + i * 4 + wid;
        const bf16* p = a + (long long)row * lda_ + d0;
        float xv[12];
#pragma unroll
        for (int k = 0; k < 12; k += 4) {
            const bf16x4 v = *(const bf16x4*)(p + k);
            xv[k] = (float)v[0]; xv[k+1] = (float)v[1];
            xv[k+2] = (float)v[2]; xv[k+3] = (float)v[3];
        }
        float s1 = 0.f, s2 = 0.f;
#pragma unroll
        for (int k = 0; k < 12; ++k) { s1 += xv[k]; s2 += xv[k] * xv[k]; }
        for (int off = 32; off; off >>= 1) {
            s1 += __shfl_xor(s1, off);
            s2 += __shfl_xor(s2, off);
        }
        const float mu  = s1 * (1.0f / 768.0f);
        const float var = s2 * (1.0f / 768.0f) - mu * mu;
        const float rs  = rsqrtf(var + 1e-5f);
        bf16* po = o + (long long)row * ldo + d0;
#pragma unroll
        for (int k = 0; k < 12; k += 4) {
            bf16x4 ov;
            ov[0] = (bf16)((xv[k]   - mu) * rs * gv[k]   + ev[k]);
            ov[1] = (bf16)((xv[k+1] - mu) * rs * gv[k+1] + ev[k+1]);
            ov[2] = (bf16)((xv[k+2] - mu) * rs * gv[k+2] + ev[k+2]);
            ov[3] = (bf16)((xv[k+3] - mu) * rs * gv[k+3] + ev[k+3]);
            *(bf16x4*)(po + k) = ov;
        }
    }
}

// ---------------------------------------------------------------------------
// LN2 fused with s-sum (wave-parallel, R10-verified).
// ---------------------------------------------------------------------------
__global__ __launch_bounds__(256)
void ln2_reduce_kernel(const bf16* __restrict__ src,  /* ffn+x1, ld 3072 */
                       const float* __restrict__ g, const float* __restrict__ be,
                       float* __restrict__ partial)
{
    const int blk  = blockIdx.x;          // 0..511 (32 rows each)
    const int tid  = threadIdx.x;
    const int wid  = tid >> 6, lane = tid & 63;
    const int d0   = lane * 12;

    float gv[12], ev[12];
#pragma unroll
    for (int k = 0; k < 12; k += 4) {
        *(float4*)(gv + k) = *(const float4*)(g + d0 + k);
        *(float4*)(ev + k) = *(const float4*)(be + d0 + k);
    }
    float acc[12];
#pragma unroll
    for (int k = 0; k < 12; ++k) acc[k] = 0.f;

    for (int i = 0; i < 8; ++i) {
        const int row = blk * 32 + i * 4 + wid;
        const bf16* p = src + (long long)row * 3072 + d0;
        float xv[12];
#pragma unroll
        for (int k = 0; k < 12; k += 4) {
            const bf16x4 v = *(const bf16x4*)(p + k);
            xv[k] = (float)v[0]; xv[k+1] = (float)v[1];
            xv[k+2] = (float)v[2]; xv[k+3] = (float)v[3];
        }
        float s1 = 0.f, s2 = 0.f;
#pragma unroll
        for (int k = 0; k < 12; ++k) { s1 += xv[k]; s2 += xv[k] * xv[k]; }
        for (int off = 32; off; off >>= 1) {
            s1 += __shfl_xor(s1, off);
            s2 += __shfl_xor(s2, off);
        }
        const float mu  = s1 * (1.0f / 768.0f);
        const float var = s2 * (1.0f / 768.0f) - mu * mu;
        const float rs  = rsqrtf(var + 1e-5f);
#pragma unroll
        for (int k = 0; k < 12; ++k) acc[k] += (xv[k] - mu) * rs * gv[k] + ev[k];
    }

    __shared__ float red[4][768];
#pragma unroll
    for (int k = 0; k < 12; k += 4)
        *(float4*)(&red[wid][d0 + k]) = *(const float4*)(acc + k);
    __syncthreads();
    if (wid == 0) {
#pragma unroll
        for (int k = 0; k < 12; k += 4) {
            const float4 a0 = *(const float4*)(&red[0][d0 + k]);
            const float4 a1 = *(const float4*)(&red[1][d0 + k]);
            const float4 a2 = *(const float4*)(&red[2][d0 + k]);
            const float4 a3 = *(const float4*)(&red[3][d0 + k]);
            *(float4*)(partial + (long long)blk * 768 + d0 + k) =
                make_float4(a0.x + a1.x + a2.x + a3.x, a0.y + a1.y + a2.y + a3.y,
                            a0.z + a1.z + a2.z + a3.z, a0.w + a1.w + a2.w + a3.w);
        }
    }
}

// stage 2
__global__ __launch_bounds__(192)
void reduce_fc2_stage2_kernel(const float* __restrict__ partial, const float* __restrict__ w,
                              const float* __restrict__ bias, float* __restrict__ out)
{
    const int b = blockIdx.x, t = threadIdx.x;
    const int d0 = t * 4;
    float a[4] = {0.f, 0.f, 0.f, 0.f};
    for (int c = 0; c < 16; ++c) {
        const float4 pv = *(const float4*)(partial + (long long)(b * 16 + c) * 768 + d0);
        a[0] += pv.x; a[1] += pv.y; a[2] += pv.z; a[3] += pv.w;
    }
    __shared__ float os[10];
    if (t < 10) os[t] = 0.f;
    __syncthreads();
    for (int c = 0; c < 10; ++c) {
        const float4 wv = *(const float4*)(w + c * 768 + d0);
        float p = wv.x * a[0] + wv.y * a[1] + wv.z * a[2] + wv.w * a[3];
        for (int off = 32; off; off >>= 1) p += __shfl_xor(p, off);
        if ((t & 63) == 0) atomicAdd(&os[c], p);
    }
    __syncthreads();
    if (t < 10) out[b * 10 + t] = os[t] + bias[t];
}

// ---------------------------------------------------------------------------
// workspace layout (bytes)
// ---------------------------------------------------------------------------
static const size_t OFF_XPE  = 0;
static const size_t OFF_WCAT = OFF_XPE  + (size_t)16384 * 768 * 2;
static const size_t OFF_WT3  = OFF_WCAT + (size_t)3072 * 768 * 2;
static const size_t OFF_INPJ = OFF_WT3  + (size_t)3 * 768 * 768 * 2;
static const size_t OFF_WOUT = OFF_INPJ + (size_t)2304 * 768 * 2;
static const size_t OFF_WF1A = OFF_WOUT + (size_t)768 * 768 * 2;
static const size_t OFF_WF1B = OFF_WF1A + (size_t)768 * 768 * 2;
static const size_t OFF_BCAT = OFF_WF1B + (size_t)768 * 768 * 2;
static const size_t OFF_QKVX = OFF_BCAT + (size_t)3072 * 4;
static const size_t OFF_VT   = OFF_QKVX + (size_t)16384 * 3072 * 2;   // unused (R13)
static const size_t OFF_S    = OFF_VT   + (size_t)128 * 192 * 512 * 2; // fc2 partials
static const size_t OFF_X1   = OFF_S    + (size_t)128 * 512 * 512 * 2;

extern "C" void kernel_launch(void* const* d_in, const int* in_sizes, int n_in,
                              void* d_out, int out_size, void* d_ws, size_t ws_size,
                              hipStream_t stream)
{
    const float* x     = (const float*)d_in[0];
    const float* wq    = (const float*)d_in[1];
    const float* bq    = (const float*)d_in[2];
    const float* wk    = (const float*)d_in[3];
    const float* bk    = (const float*)d_in[4];
    const float* wv    = (const float*)d_in[5];
    const float* bv    = (const float*)d_in[6];
    const float* wx    = (const float*)d_in[7];
    const float* bx    = (const float*)d_in[8];
    const float* inpw  = (const float*)d_in[9];
    const float* inpb  = (const float*)d_in[10];
    const float* woutp = (const float*)d_in[11];
    const float* boutp = (const float*)d_in[12];
    const float* wf1a  = (const float*)d_in[13];
    const float* bf1a  = (const float*)d_in[14];
    const float* wf1b  = (const float*)d_in[15];
    const float* bf1b  = (const float*)d_in[16];
    const float* lng   = (const float*)d_in[17];
    const float* lnb   = (const float*)d_in[18];
    const float* wfc2  = (const float*)d_in[19];
    const float* bfc2  = (const float*)d_in[20];
    float* out = (float*)d_out;

    char* ws = (char*)d_ws;
    bf16*  XPE  = (bf16*)(ws + OFF_XPE);
    bf16*  WCAT = (bf16*)(ws + OFF_WCAT);
    bf16*  WT3  = (bf16*)(ws + OFF_WT3);
    bf16*  INPJ = (bf16*)(ws + OFF_INPJ);
    bf16*  WOUT = (bf16*)(ws + OFF_WOUT);
    bf16*  WF1A = (bf16*)(ws + OFF_WF1A);
    bf16*  WF1B = (bf16*)(ws + OFF_WF1B);
    float* BCAT = (float*)(ws + OFF_BCAT);
    bf16*  QKVX = (bf16*)(ws + OFF_QKVX);
    float* PART = (float*)(ws + OFF_S);
    bf16*  X1   = (bf16*)(ws + OFF_X1);

    // ---- prep: weights + bias + x+PE (single dispatch) ----
    prep_kernel<<<18339, 256, 0, stream>>>(wq, wk, wv, wx, inpw, inpb,
                                           bq, bk, bv, bx, woutp, wf1a, wf1b, x,
                                           WT3, INPJ, WOUT, WF1A, WF1B,
                                           WCAT + (size_t)2304 * 768, BCAT, XPE);

    // W_eff[z] = in_proj_w[z] @ w{q,k,v}
    gemm_nt<64, 128, 2, 4><<<dim3(6, 12, 3), 256, 0, stream>>>(
        INPJ, WT3, WCAT, nullptr, 768, 768, 768, 768,
        1, 589824, 0, 589824, 0, 589824, 0, 1.0f, 0, nullptr, 0);

    // QKVX = XPE @ WCAT^T + BCAT -> [16384,3072]
    // R23: reverted to R15 fenced flow (measured best: 82.5-83.6 us).
    gemm_qkv_8ph<<<dim3(12, 64, 1), 512, 0, stream>>>(XPE, WCAT, QKVX, BCAT);

    // fused attention (R18 version):
    // Q2 region overwritten with ctx
    fused_attn_kernel<<<512, 256, 0, stream>>>(QKVX);

    // attn_out + XR residual -> K2 region  (R23: swapped grid — A-panel
    // sharers co-XCD)
    gemm_flow<<<dim3(64, 4, 1), 512, 0, stream>>>(
        QKVX, WOUT, QKVX + 768, boutp, 3072, 768, 3072,
        0, QKVX + 2304, 3072);

    // x1 = LN(attn_out + XR)  (R19: 32 rows/block)
    ln1_kernel<<<512, 256, 0, stream>>>(QKVX + 768, 3072, X1, 768, lng, lnb);

    // h1 = relu(x1 @ fc1a^T + b) -> V2 region  (R23 swapped grid)
    gemm_flow<<<dim3(64, 4, 1), 512, 0, stream>>>(
        X1, WF1A, QKVX + 1536, bf1a, 768, 768, 3072,
        1, nullptr, 0);

    // ffn + x1 residual -> XR region  (R23 swapped grid)
    gemm_flow<<<dim3(64, 4, 1), 512, 0, stream>>>(
        QKVX + 1536, WF1B, QKVX + 2304, bf1b, 3072, 768, 3072,
        0, X1, 768);

    // LN2 + s-sum fused (x2 never materialized)
    ln2_reduce_kernel<<<512, 256, 0, stream>>>(QKVX + 2304, lng, lnb, PART);

    // out = partial-sum @ fc2^T + b
    reduce_fc2_stage2_kernel<<<32, 192, 0, stream>>>(PART, wfc2, bfc2, out);
}

// Round 11
// 426.992 us; speedup vs baseline: 1.0739x; 1.0373x over previous
//
#include <hip/hip_runtime.h>
#include <hip/hip_bf16.h>

typedef __bf16 bf16;
typedef __bf16 bf16x8 __attribute__((ext_vector_type(8)));
typedef __bf16 bf16x4 __attribute__((ext_vector_type(4)));
typedef __bf16 bf16x2 __attribute__((ext_vector_type(2)));
typedef float  f32x4  __attribute__((ext_vector_type(4)));

#define GLD16(g, l) __builtin_amdgcn_global_load_lds(                        \
    (const __attribute__((address_space(1))) void*)(g),                      \
    (__attribute__((address_space(3))) void*)(l), 16, 0, 0)

// ---------------------------------------------------------------------------
// NT GEMM: C[m,n] = alpha * sum_k A[m,k]*B[n,k] (+ bias[n]) (+ relu) (+ res)
// BK=64; swizzled LDS (conflict-free, R2); pointer-bump staging (R3).
// Still used for the small batched W_eff GEMM only (R16).
// ---------------------------------------------------------------------------
template<int BM, int BN, int MFR, int NFR>
__global__ __launch_bounds__(256, 3)
void gemm_nt(const bf16* __restrict__ A, const bf16* __restrict__ B,
             bf16* __restrict__ C, const float* __restrict__ bias,
             int K, int lda, int ldb, int ldc,
             int inner,
             long long aOut, long long aIn,
             long long bOut, long long bIn,
             long long cOut, long long cIn,
             float alpha, int relu,
             const bf16* __restrict__ res, int ldr)
{
    const int z  = blockIdx.z;
    const int zo = z / inner;
    const int zi = z - zo * inner;
    A += (long long)zo * aOut + (long long)zi * aIn;
    B += (long long)zo * bOut + (long long)zi * bIn;
    C += (long long)zo * cOut + (long long)zi * cIn;

    const int tm = blockIdx.y * BM;
    const int tn = blockIdx.x * BN;

    __shared__ __align__(16) bf16 smem[(BM + BN) * 64];
    bf16* As = smem;
    bf16* Bs = smem + BM * 64;

    const int tid  = threadIdx.x;
    const int lane = tid & 63;
    const int wid  = tid >> 6;
    const int wr   = wid >> 1;
    const int wc   = wid & 1;

    f32x4 acc[MFR][NFR];
#pragma unroll
    for (int i = 0; i < MFR; ++i)
#pragma unroll
        for (int j = 0; j < NFR; ++j) acc[i][j] = (f32x4){0.f, 0.f, 0.f, 0.f};

    const int srow = lane >> 3;
    const int gch8 = ((lane & 7) ^ srow) * 8;

    const int NA = BM / 32;
    const int NB = BN / 32;

    const bf16* aP[NA];
#pragma unroll
    for (int jj = 0; jj < NA; ++jj) {
        const int R0 = (wid * NA + jj) * 8;
        aP[jj] = A + (long long)(tm + R0 + srow) * lda + gch8;
    }
    const bf16* bP[NB];
#pragma unroll
    for (int jj = 0; jj < NB; ++jj) {
        const int R0 = (wid * NB + jj) * 8;
        bP[jj] = B + (long long)(tn + R0 + srow) * ldb + gch8;
    }

    const int lr = lane & 15;
    const int qg = lane >> 4;

    for (int kt = 0; kt < K; kt += 64) {
#pragma unroll
        for (int jj = 0; jj < NA; ++jj)
            GLD16(aP[jj], As + (wid * NA + jj) * 512);
#pragma unroll
        for (int jj = 0; jj < NB; ++jj)
            GLD16(bP[jj], Bs + (wid * NB + jj) * 512);
        __syncthreads();

#pragma unroll
        for (int h = 0; h < 2; ++h) {
            const int off = ((qg + h * 4) ^ (lr & 7)) * 8;
            bf16x8 af[MFR], bfr[NFR];
#pragma unroll
            for (int i = 0; i < MFR; ++i)
                af[i] = *(const bf16x8*)(As + (wr * MFR * 16 + i * 16 + lr) * 64 + off);
#pragma unroll
            for (int j = 0; j < NFR; ++j)
                bfr[j] = *(const bf16x8*)(Bs + (wc * NFR * 16 + j * 16 + lr) * 64 + off);
#pragma unroll
            for (int i = 0; i < MFR; ++i)
#pragma unroll
                for (int j = 0; j < NFR; ++j)
                    acc[i][j] = __builtin_amdgcn_mfma_f32_16x16x32_bf16(
                        af[i], bfr[j], acc[i][j], 0, 0, 0);
        }
        __syncthreads();
#pragma unroll
        for (int jj = 0; jj < NA; ++jj) aP[jj] += 64;
#pragma unroll
        for (int jj = 0; jj < NB; ++jj) bP[jj] += 64;
    }

#pragma unroll
    for (int i = 0; i < MFR; ++i) {
#pragma unroll
        for (int j = 0; j < NFR; ++j) {
            const int mm0 = tm + wr * MFR * 16 + i * 16 + (lane >> 4) * 4;
            const int nn  = tn + wc * NFR * 16 + j * 16 + (lane & 15);
#pragma unroll
            for (int r = 0; r < 4; ++r) {
                float v = acc[i][j][r] * alpha;
                if (bias) v += bias[nn];
                if (res)  v += (float)res[(long long)(mm0 + r) * ldr + nn];
                if (relu) v = fmaxf(v, 0.f);
                C[(long long)(mm0 + r) * ldc + nn] = (bf16)v;
            }
        }
    }
}

// ---------------------------------------------------------------------------
// R23: QKV + mids on the R15/R18-measured fenced flow schedule (measured
// best: QKV 82.2-83.6 us, MfmaUtil 39-40 across 4 healthy runs).  Schedule
// variants R14/R19/R21/R22 all refuted; QKV schedule-search closed.
// ---------------------------------------------------------------------------
#define BAR8()  __builtin_amdgcn_s_barrier()
#define LGKM0() do { asm volatile("s_waitcnt lgkmcnt(0)" ::: "memory");      \
                     __builtin_amdgcn_sched_barrier(0); } while (0)

#define RD_A(S, MB)                                                          \
    _Pragma("unroll") for (int mi = 0; mi < 4; ++mi)                         \
    _Pragma("unroll") for (int h = 0; h < 2; ++h)                            \
        af[mi][h] = *(const bf16x8*)((S) + aBase + ((MB) + mi) * 1024 +      \
                                     (h ? koff1 : koff0));

#define RD_B(S, NJ)                                                          \
    _Pragma("unroll") for (int h = 0; h < 2; ++h)                            \
        bfv[NJ][h] = *(const bf16x8*)((S) + bBase + (NJ) * 1024 +            \
                                      (h ? koff1 : koff0));

#define MFMA_Q(MB, N0, N1)                                                   \
    __builtin_amdgcn_s_setprio(1);                                          \
    _Pragma("unroll") for (int h = 0; h < 2; ++h)                            \
    _Pragma("unroll") for (int mi = 0; mi < 4; ++mi) {                       \
        acc[(MB)+mi][(N0)] = __builtin_amdgcn_mfma_f32_16x16x32_bf16(        \
            af[mi][h], bfv[(N0)][h], acc[(MB)+mi][(N0)], 0, 0, 0);           \
        acc[(MB)+mi][(N1)] = __builtin_amdgcn_mfma_f32_16x16x32_bf16(        \
            af[mi][h], bfv[(N1)][h], acc[(MB)+mi][(N1)], 0, 0, 0);           \
    }                                                                        \
    __builtin_amdgcn_s_setprio(0);

#define MFMA_Q1(MB, N0)                                                      \
    __builtin_amdgcn_s_setprio(1);                                          \
    _Pragma("unroll") for (int h = 0; h < 2; ++h)                            \
    _Pragma("unroll") for (int mi = 0; mi < 4; ++mi) {                       \
        acc[(MB)+mi][(N0)] = __builtin_amdgcn_mfma_f32_16x16x32_bf16(        \
            af[mi][h], bfv[(N0)][h], acc[(MB)+mi][(N0)], 0, 0, 0);           \
    }                                                                        \
    __builtin_amdgcn_s_setprio(0);

#define STAGE_A(DST)                                                         \
    _Pragma("unroll") for (int jj = 0; jj < 4; ++jj) {                       \
        GLD16(aP[jj], (DST) + (wid * 4 + jj) * 512);  aP[jj] += 64; }

#define STAGE_B(DST)                                                         \
    _Pragma("unroll") for (int jj = 0; jj < 4; ++jj) {                       \
        GLD16(bP[jj], (DST) + 16384 + (wid * 4 + jj) * 512);  bP[jj] += 64; }

#define STAGE_B3(DST)                                                        \
    _Pragma("unroll") for (int jj = 0; jj < 3; ++jj) {                       \
        GLD16(bP[jj], (DST) + 16384 + (wid * 3 + jj) * 512);  bP[jj] += 64; }

#define K_TILE_F(CUR, NXT, STG, LAST)                                        \
  {                                                                          \
    RD_A((CUR), 0); RD_B((CUR), 0); RD_B((CUR), 1);                          \
    if (STG) { STAGE_A(NXT) }                                                \
    LGKM0();                                                                 \
    MFMA_Q(0, 0, 1)                                                          \
    RD_B((CUR), 2); RD_B((CUR), 3);                                          \
    if (STG) { STAGE_B(NXT) }                                                \
    LGKM0();                                                                 \
    MFMA_Q(0, 2, 3)                                                          \
    RD_A((CUR), 4);                                                          \
    LGKM0();                                                                 \
    MFMA_Q(4, 2, 3)                                                          \
    MFMA_Q(4, 0, 1)                                                          \
    if (!(LAST)) { asm volatile("s_waitcnt vmcnt(0)" ::: "memory");          \
                   __builtin_amdgcn_sched_barrier(0); BAR8(); }              \
  }

// BN=192 variant (3 n-frags/wave), B staged with 3 GLD16/thread.
#define K_TILE_F3(CUR, NXT, STG, LAST)                                       \
  {                                                                          \
    RD_A((CUR), 0); RD_B((CUR), 0); RD_B((CUR), 1);                          \
    if (STG) { STAGE_A(NXT) }                                                \
    LGKM0();                                                                 \
    MFMA_Q(0, 0, 1)                                                          \
    RD_B((CUR), 2);                                                          \
    if (STG) { STAGE_B3(NXT) }                                               \
    LGKM0();                                                                 \
    MFMA_Q1(0, 2)                                                            \
    RD_A((CUR), 4);                                                          \
    LGKM0();                                                                 \
    MFMA_Q1(4, 2)                                                            \
    MFMA_Q(4, 0, 1)                                                          \
    if (!(LAST)) { asm volatile("s_waitcnt vmcnt(0)" ::: "memory");          \
                   __builtin_amdgcn_sched_barrier(0); BAR8(); }              \
  }

__global__ __launch_bounds__(512, 2)
void gemm_qkv_8ph(const bf16* __restrict__ A, const bf16* __restrict__ B,
                  bf16* __restrict__ C, const float* __restrict__ bias)
{
    constexpr int LDA = 768, LDB = 768, LDC = 3072;
    const int tm = blockIdx.y * 256;
    const int tn = blockIdx.x * 256;

    __shared__ __align__(16) bf16 smem[2][2 * 256 * 64];   // 128 KiB

    const int tid  = threadIdx.x;
    const int lane = tid & 63;
    const int wid  = tid >> 6;       // 0..7
    const int wr   = wid >> 2;       // 0..1  (m-half of block tile)
    const int wc   = wid & 3;        // 0..3  (n-quarter)
    const int lr   = lane & 15;
    const int qg   = lane >> 4;

    // staging (pre-swizzled global source, linear LDS dest: LDS[row][c] =
    // G[row][c ^ (row&7)])
    const int srow = lane >> 3;
    const int gch8 = ((lane & 7) ^ srow) * 8;
    const bf16* aP[4];
    const bf16* bP[4];
#pragma unroll
    for (int jj = 0; jj < 4; ++jj) {
        aP[jj] = A + (long long)(tm + wid * 32 + jj * 8 + srow) * LDA + gch8;
        bP[jj] = B + (long long)(tn + wid * 32 + jj * 8 + srow) * LDB + gch8;
    }

    f32x4 acc[8][4];
#pragma unroll
    for (int i = 0; i < 8; ++i)
#pragma unroll
        for (int j = 0; j < 4; ++j) acc[i][j] = (f32x4){0.f, 0.f, 0.f, 0.f};

    const int aBase = (wr * 128 + lr) * 64;
    const int bBase = 16384 + (wc * 64 + lr) * 64;
    const int koff0 = ((qg    ) ^ (lr & 7)) * 8;
    const int koff1 = ((qg + 4) ^ (lr & 7)) * 8;

    bf16x8 af[4][2];     // current A m-half (lo in bursts 0-1, hi in burst 2)
    bf16x8 bfv[4][2];    // all 4 B n-frags live across the K-tile

    bf16* S0 = &smem[0][0];
    bf16* S1 = &smem[1][0];

    // prologue: stage tile 0 into S0, drain, converge
    STAGE_A(S0)
    STAGE_B(S0)
    asm volatile("s_waitcnt vmcnt(0)" ::: "memory");
    BAR8();

    // K = 768 -> 12 K-tiles.  Tiles 0..10 stage tile kt+1 into the other
    // buffer; tile 11 computes only.
#pragma unroll 1
    for (int it = 0; it < 5; ++it) {
        K_TILE_F(S0, S1, 1, 0)
        K_TILE_F(S1, S0, 1, 0)
    }
    K_TILE_F(S0, S1, 1, 0)
    K_TILE_F(S1, S0, 0, 1)

    // epilogue
    float bv[4];
#pragma unroll
    for (int j = 0; j < 4; ++j) bv[j] = bias[tn + wc * 64 + j * 16 + lr];

#pragma unroll
    for (int i = 0; i < 8; ++i) {
        const int mm0 = tm + wr * 128 + i * 16 + qg * 4;
#pragma unroll
        for (int j = 0; j < 4; ++j) {
            const int nn = tn + wc * 64 + j * 16 + lr;
#pragma unroll
            for (int r = 0; r < 4; ++r)
                C[(long long)(mm0 + r) * LDC + nn] = (bf16)(acc[i][j][r] + bv[j]);
        }
    }
}

// ---------------------------------------------------------------------------
// R16/R18/R23: flow-schedule GEMM for the three mid GEMMs (M=16384, N=768,
// K=768).  256x192 tile, 256 blocks = 100% CU fill.  Grid dim3(64,4):
// tm <- x, tn <- y (A-panel sharers co-XCD; ~neutral but kept).
// ---------------------------------------------------------------------------
__global__ __launch_bounds__(512, 2)
void gemm_flow(const bf16* __restrict__ A, const bf16* __restrict__ B,
               bf16* __restrict__ C, const float* __restrict__ bias,
               int lda, int ldb, int ldc, int relu,
               const bf16* __restrict__ res, int ldr)
{
    const int tm = blockIdx.x * 256;    // m-tile on x (fastest)
    const int tn = blockIdx.y * 192;    // n-tile on y

    __shared__ __align__(16) bf16 smem[2][(256 + 192) * 64];   // 112 KiB

    const int tid  = threadIdx.x;
    const int lane = tid & 63;
    const int wid  = tid >> 6;       // 0..7
    const int wr   = wid >> 2;       // 0..1
    const int wc   = wid & 3;        // 0..3
    const int lr   = lane & 15;
    const int qg   = lane >> 4;

    const int srow = lane >> 3;
    const int gch8 = ((lane & 7) ^ srow) * 8;
    const bf16* aP[4];
    const bf16* bP[3];
#pragma unroll
    for (int jj = 0; jj < 4; ++jj)
        aP[jj] = A + (long long)(tm + wid * 32 + jj * 8 + srow) * lda + gch8;
#pragma unroll
    for (int jj = 0; jj < 3; ++jj)
        bP[jj] = B + (long long)(tn + wid * 24 + jj * 8 + srow) * ldb + gch8;

    f32x4 acc[8][3];
#pragma unroll
    for (int i = 0; i < 8; ++i)
#pragma unroll
        for (int j = 0; j < 3; ++j) acc[i][j] = (f32x4){0.f, 0.f, 0.f, 0.f};

    const int aBase = (wr * 128 + lr) * 64;
    const int bBase = 16384 + (wc * 48 + lr) * 64;
    const int koff0 = ((qg    ) ^ (lr & 7)) * 8;
    const int koff1 = ((qg + 4) ^ (lr & 7)) * 8;

    bf16x8 af[4][2];
    bf16x8 bfv[3][2];

    bf16* S0 = &smem[0][0];
    bf16* S1 = &smem[1][0];

    STAGE_A(S0)
    STAGE_B3(S0)
    asm volatile("s_waitcnt vmcnt(0)" ::: "memory");
    BAR8();

#pragma unroll 1
    for (int it = 0; it < 5; ++it) {
        K_TILE_F3(S0, S1, 1, 0)
        K_TILE_F3(S1, S0, 1, 0)
    }
    K_TILE_F3(S0, S1, 1, 0)
    K_TILE_F3(S1, S0, 0, 1)

    // epilogue: bias (+res) (+relu)
    float bv[3];
#pragma unroll
    for (int j = 0; j < 3; ++j) bv[j] = bias ? bias[tn + wc * 48 + j * 16 + lr] : 0.f;

#pragma unroll
    for (int i = 0; i < 8; ++i) {
        const int mm0 = tm + wr * 128 + i * 16 + qg * 4;
#pragma unroll
        for (int j = 0; j < 3; ++j) {
            const int nn = tn + wc * 48 + j * 16 + lr;
#pragma unroll
            for (int r = 0; r < 4; ++r) {
                float v = acc[i][j][r] + bv[j];
                if (res)  v += (float)res[(long long)(mm0 + r) * ldr + nn];
                if (relu) v = fmaxf(v, 0.f);
                C[(long long)(mm0 + r) * ldc + nn] = (bf16)v;
            }
        }
    }
}

// ---------------------------------------------------------------------------
// Fused flash-style attention (R6-verified; R13 V^T staging fused in).
// R20: R18 version.  R19's Pb-alias required a mid-tile lockstep barrier
// (cost ~10 us); R17's reg-prefetch spilled (zero VGPR headroom).  Frozen.
// ---------------------------------------------------------------------------
__global__ __launch_bounds__(256, 2)
void fused_attn_kernel(bf16* __restrict__ qkvx)
{
    const int flat = blockIdx.x;                     // 0..511
    const int qt = (flat >> 3) & 3;                  // q-tile
    const int z  = (flat & 7) | ((flat >> 5) << 3);  // b*4 + h
    const int b  = z >> 2, h = z & 3;

    const bf16* Qg = qkvx + (long long)b * 512 * 3072 + h * 192;
    const bf16* Kg = Qg + 768;
    const bf16* Vg = Qg + 1536;                      // [s][d] rows, ld 3072

    __shared__ __align__(16) bf16 Ks[64 * 192];    // [key][d], 24ch rows, XOR-swz
    __shared__ __align__(16) bf16 VTs[192 * 64];   // [d][key], 8ch rows, XOR-swz
    __shared__ __align__(16) bf16 Pb[4 * 32 * 64]; // per-wave [m][key], XOR-swz

    const int tid  = threadIdx.x;
    const int lane = tid & 63;
    const int wid  = tid >> 6;
    const int lr   = lane & 15;
    const int qg   = lane >> 4;
    const int m0   = qt * 128 + wid * 32;

    bf16x8 qf[2][6];
#pragma unroll
    for (int mt = 0; mt < 2; ++mt)
#pragma unroll
        for (int t = 0; t < 6; ++t)
            qf[mt][t] = *(const bf16x8*)(Qg + (long long)(m0 + mt * 16 + lr) * 3072
                                         + t * 32 + qg * 8);

    const bf16* kP[6];
#pragma unroll
    for (int i = 0; i < 6; ++i) {
        const int c = i * 256 + tid;
        const int krow = c / 24, kcc = c % 24;
        const int kgc  = (kcc & 24) | ((kcc & 7) ^ (krow & 7));
        kP[i] = Kg + (long long)krow * 3072 + kgc * 8;
    }
    // V transpose staging indices (fixed per thread)
    const int vkp = tid & 31;        // key pair 0..31 -> keys 2vkp, 2vkp+1
    const int vdc = tid >> 5;        // d-chunk base (+8 per i)

    f32x4 acc[2][12];
#pragma unroll
    for (int mt = 0; mt < 2; ++mt)
#pragma unroll
        for (int dt = 0; dt < 12; ++dt) acc[mt][dt] = (f32x4){0.f, 0.f, 0.f, 0.f};
    float mrow[2][4], lrow[2][4];
#pragma unroll
    for (int mt = 0; mt < 2; ++mt)
#pragma unroll
        for (int r = 0; r < 4; ++r) { mrow[mt][r] = -3e38f; lrow[mt][r] = 0.f; }

    const float alpha = 0.0721687836f;   // 1/sqrt(192)

    for (int kt = 0; kt < 8; ++kt) {
#pragma unroll
        for (int i = 0; i < 6; ++i)
            GLD16(kP[i], Ks + (i * 256 + wid * 64) * 8);
        // ---- V^T staging: 2 rows x 8 d, packed bf16x2 stores ----
#pragma unroll
        for (int i = 0; i < 3; ++i) {
            const int dc = vdc + i * 8;                  // 0..23
            const bf16* p = Vg + (long long)(2 * vkp) * 3072 + dc * 8;
            const bf16x8 v0 = *(const bf16x8*)(p);
            const bf16x8 v1 = *(const bf16x8*)(p + 3072);
#pragma unroll
            for (int j = 0; j < 8; ++j) {
                const int d = dc * 8 + j;
                bf16x2 pk; pk[0] = v0[j]; pk[1] = v1[j];
                *(bf16x2*)(VTs + d * 64 + ((vkp >> 2) ^ (d & 7)) * 8
                           + 2 * (vkp & 3)) = pk;
            }
        }
        __syncthreads();

        f32x4 sf[2][4];
#pragma unroll
        for (int mt = 0; mt < 2; ++mt)
#pragma unroll
            for (int nt = 0; nt < 4; ++nt) sf[mt][nt] = (f32x4){0.f, 0.f, 0.f, 0.f};
#pragma unroll
        for (int nt = 0; nt < 4; ++nt) {
#pragma unroll
            for (int t = 0; t < 6; ++t) {
                const int ch = t * 4 + qg;
                const int ph = (ch & 24) | ((ch & 7) ^ (lr & 7));
                const bf16x8 kf = *(const bf16x8*)(Ks + (nt * 16 + lr) * 192 + ph * 8);
                sf[0][nt] = __builtin_amdgcn_mfma_f32_16x16x32_bf16(qf[0][t], kf, sf[0][nt], 0, 0, 0);
                sf[1][nt] = __builtin_amdgcn_mfma_f32_16x16x32_bf16(qf[1][t], kf, sf[1][nt], 0, 0, 0);
            }
        }

#pragma unroll
        for (int mt = 0; mt < 2; ++mt) {
            float mx[4], a[4], rs[4], p[4][4];
#pragma unroll
            for (int r = 0; r < 4; ++r) {
                float v0 = fmaxf(sf[mt][0][r], sf[mt][1][r]);
                float v1 = fmaxf(sf[mt][2][r], sf[mt][3][r]);
                mx[r] = fmaxf(v0, v1) * alpha;
            }
#pragma unroll
            for (int msk = 1; msk <= 8; msk <<= 1)
#pragma unroll
                for (int r = 0; r < 4; ++r) mx[r] = fmaxf(mx[r], __shfl_xor(mx[r], msk));
#pragma unroll
            for (int r = 0; r < 4; ++r) {
                const float mn = fmaxf(mrow[mt][r], mx[r]);
                a[r] = __expf(mrow[mt][r] - mn);
                mrow[mt][r] = mn;
                rs[r] = 0.f;
            }
#pragma unroll
            for (int nt = 0; nt < 4; ++nt)
#pragma unroll
                for (int r = 0; r < 4; ++r) {
                    p[nt][r] = __expf(sf[mt][nt][r] * alpha - mrow[mt][r]);
                    rs[r] += p[nt][r];
                }
#pragma unroll
            for (int msk = 1; msk <= 8; msk <<= 1)
#pragma unroll
                for (int r = 0; r < 4; ++r) rs[r] += __shfl_xor(rs[r], msk);
#pragma unroll
            for (int r = 0; r < 4; ++r) lrow[mt][r] = lrow[mt][r] * a[r] + rs[r];
#pragma unroll
            for (int dt = 0; dt < 12; ++dt)
#pragma unroll
                for (int r = 0; r < 4; ++r) acc[mt][dt][r] *= a[r];
#pragma unroll
            for (int nt = 0; nt < 4; ++nt)
#pragma unroll
                for (int r = 0; r < 4; ++r) {
                    const int row = mt * 16 + qg * 4 + r;
                    const int ph2 = (nt * 2 + (lr >> 3)) ^ (row & 7);
                    Pb[wid * 2048 + row * 64 + ph2 * 8 + (lr & 7)] = (bf16)p[nt][r];
                }
        }

        bf16x8 pf[2][2];
#pragma unroll
        for (int mt = 0; mt < 2; ++mt)
#pragma unroll
            for (int ks = 0; ks < 2; ++ks) {
                const int row = mt * 16 + lr;
                const int ph  = (ks * 4 + qg) ^ (lr & 7);
                pf[mt][ks] = *(const bf16x8*)(Pb + wid * 2048 + row * 64 + ph * 8);
            }
#pragma unroll
        for (int dt = 0; dt < 12; ++dt) {
#pragma unroll
            for (int ks = 0; ks < 2; ++ks) {
                const int ph = (ks * 4 + qg) ^ (lr & 7);
                const bf16x8 vf = *(const bf16x8*)(VTs + (dt * 16 + lr) * 64 + ph * 8);
                acc[0][dt] = __builtin_amdgcn_mfma_f32_16x16x32_bf16(pf[0][ks], vf, acc[0][dt], 0, 0, 0);
                acc[1][dt] = __builtin_amdgcn_mfma_f32_16x16x32_bf16(pf[1][ks], vf, acc[1][dt], 0, 0, 0);
            }
        }
        __syncthreads();
#pragma unroll
        for (int i = 0; i < 6; ++i) kP[i] += 64 * 3072;
        Vg += 64 * 3072;
    }

    bf16* Og = qkvx + (long long)b * 512 * 3072 + h * 192;
#pragma unroll
    for (int mt = 0; mt < 2; ++mt) {
        float inv[4];
#pragma unroll
        for (int r = 0; r < 4; ++r) inv[r] = 1.0f / lrow[mt][r];
#pragma unroll
        for (int dt = 0; dt < 12; ++dt)
#pragma unroll
            for (int r = 0; r < 4; ++r) {
                const int row = m0 + mt * 16 + qg * 4 + r;
                Og[(long long)row * 3072 + dt * 16 + lr] = (bf16)(acc[mt][dt][r] * inv[r]);
            }
    }
}

// ---------------------------------------------------------------------------
// R24: PE table precompute — 512x768 sinusoidal PE values depend only on
// (s mod 512, d) but were recomputed 32x (once per batch) with full-range
// sincosf inside prep's XPE section (6.3M sincos pairs, VALU-bound; the
// m205 trap).  This kernel computes the table ONCE (196k sincos pairs,
// ~2 us); prep then streams x + table (bit-identical arguments -> bit-
// identical values).
// ---------------------------------------------------------------------------
__global__ __launch_bounds__(256)
void pe_kernel(float* __restrict__ pet)
{
    const int idx4 = (blockIdx.x * 256 + threadIdx.x) * 4;   // 0..393212
    const int d    = idx4 % 768;
    const int s    = idx4 / 768;                              // 0..511
    const float ksc = -0.034603417655076f;  // -2*log2(10000)/768
    float a0 = (float)s * exp2f((float)d * ksc);
    float a1 = (float)s * exp2f((float)(d + 2) * ksc);
    float s0, c0, s1, c1;
    sincosf(a0, &s0, &c0);
    sincosf(a1, &s1, &c1);
    *(float4*)(pet + idx4) = make_float4(s0, c0, s1, c1);
}

// ---------------------------------------------------------------------------
// one-shot prep kernel: weight casts/transposes + fused bias + x+PE cast.
// R24: XPE section reads the precomputed PE table (streaming, ~75 MB) —
// no on-device trig.
// ---------------------------------------------------------------------------
__device__ __forceinline__ void cast4(const float* src, bf16* dst, int i)
{
    const float4 v = *(const float4*)(src + (long long)i * 4);
    bf16x4 o;
    o[0] = (bf16)v.x; o[1] = (bf16)v.y; o[2] = (bf16)v.z; o[3] = (bf16)v.w;
    *(bf16x4*)(dst + (long long)i * 4) = o;
}

__global__ __launch_bounds__(256)
void prep_kernel(const float* __restrict__ wq, const float* __restrict__ wk,
                 const float* __restrict__ wv, const float* __restrict__ wx,
                 const float* __restrict__ inpw, const float* __restrict__ inpb,
                 const float* __restrict__ bq, const float* __restrict__ bk,
                 const float* __restrict__ bv, const float* __restrict__ bx,
                 const float* __restrict__ woutp, const float* __restrict__ wf1a,
                 const float* __restrict__ wf1b, const float* __restrict__ x,
                 bf16* __restrict__ WT3, bf16* __restrict__ INPJ,
                 bf16* __restrict__ WOUT, bf16* __restrict__ WF1A,
                 bf16* __restrict__ WF1B, bf16* __restrict__ WXD,
                 float* __restrict__ BCAT, bf16* __restrict__ XPE,
                 const float* __restrict__ PET)
{
    const int blk = blockIdx.x;
    const int tid = threadIdx.x;
    __shared__ bf16 t[32][33];

    if (blk < 1728) {
        const int which = blk / 576, local = blk - which * 576;
        const float* src = (which == 0) ? wq : ((which == 1) ? wk : wv);
        bf16* dst = WT3 + (long long)which * 589824;
        const int r0 = (local / 24) * 32, c0 = (local % 24) * 32;
        const int tr = tid >> 5, tc = tid & 31;
#pragma unroll
        for (int k = 0; k < 4; ++k) {
            const int r = tr + k * 8;
            t[r][tc] = (bf16)src[(long long)(r0 + r) * 768 + c0 + tc];
        }
        __syncthreads();
#pragma unroll
        for (int k = 0; k < 4; ++k) {
            const int c = tr + k * 8;
            dst[(long long)(c0 + c) * 768 + r0 + tc] = t[tc][c];
        }
    } else if (blk < 3456) {
        cast4(inpw, INPJ, (blk - 1728) * 256 + tid);
    } else if (blk < 4032) {
        cast4(woutp, WOUT, (blk - 3456) * 256 + tid);
    } else if (blk < 4608) {
        cast4(wf1a, WF1A, (blk - 4032) * 256 + tid);
    } else if (blk < 5184) {
        cast4(wf1b, WF1B, (blk - 4608) * 256 + tid);
    } else if (blk < 5760) {
        cast4(wx, WXD, (blk - 5184) * 256 + tid);
    } else if (blk < 6051) {
        const int bl = blk - 5760;
        if (bl < 288) {
            const int g = tid >> 5, l = tid & 31;
            const int n = bl * 8 + g;
            const int zsec = n / 768;
            const float* bb = (zsec == 0) ? bq : ((zsec == 1) ? bk : bv);
            const float* wrow = inpw + (long long)n * 768;
            float s = 0.f;
            for (int d = l; d < 768; d += 32) s += wrow[d] * bb[d];
#pragma unroll
            for (int off = 16; off; off >>= 1) s += __shfl_xor(s, off);
            if (l == 0) BCAT[n] = inpb[n] + s;
        } else {
            const int n = (bl - 288) * 256 + tid;
            if (n < 768) BCAT[2304 + n] = bx[n];
        }
    } else {
        // R24: x + PE-table streaming add (no trig)
        const int idx4 = ((blk - 6051) * 256 + tid) * 4;
        const int d    = idx4 % 768;
        const int row  = idx4 / 768;
        const int s    = row & 511;
        const float4 xv = *(const float4*)(x + (long long)idx4);
        const float4 pe = *(const float4*)(PET + s * 768 + d);
        bf16x4 o;
        o[0] = (bf16)(xv.x + pe.x);
        o[1] = (bf16)(xv.y + pe.y);
        o[2] = (bf16)(xv.z + pe.z);
        o[3] = (bf16)(xv.w + pe.w);
        *(bf16x4*)(XPE + (long long)idx4) = o;
    }
}

// ---------------------------------------------------------------------------
// R19: LN1 ln2-style: 512 blocks x 256 threads, 32 rows/block, lane owns 12
// elems (24 B loads), shuffle-reduce per row.  (kept)
// ---------------------------------------------------------------------------
__global__ __launch_bounds__(256)
void ln1_kernel(const bf16* __restrict__ a, int lda_,
                bf16* __restrict__ o, int ldo,
                const float* __restrict__ g, const float* __restrict__ be)
{
    const int blk  = blockIdx.x;          // 0..511 (32 rows each)
    const int tid  = threadIdx.x;
    const int wid  = tid >> 6, lane = tid & 63;
    const int d0   = lane * 12;

    float gv[12], ev[12];
#pragma unroll
    for (int k = 0; k < 12; k += 4) {
        *(float4*)(gv + k) = *(const float4*)(g + d0 + k);
        *(float4*)(ev + k) = *(const float4*)(be + d0 + k);
    }

    for (int i = 0; i < 8; ++i) {
        const int row = blk * 32 + i * 4 + wid;
        const bf16* p = a + (long long)row * lda_ + d0;
        float xv[12];
#pragma unroll
        for (int k = 0; k < 12; k += 4) {
            const bf16x4 v = *(const bf16x4*)(p + k);
            xv[k] = (float)v[0]; xv[k+1] = (float)v[1];
            xv[k+2] = (float)v[2]; xv[k+3] = (float)v[3];
        }
        float s1 = 0.f, s2 = 0.f;
#pragma unroll
        for (int k = 0; k < 12; ++k) { s1 += xv[k]; s2 += xv[k] * xv[k]; }
        for (int off = 32; off; off >>= 1) {
            s1 += __shfl_xor(s1, off);
            s2 += __shfl_xor(s2, off);
        }
        const float mu  = s1 * (1.0f / 768.0f);
        const float var = s2 * (1.0f / 768.0f) - mu * mu;
        const float rs  = rsqrtf(var + 1e-5f);
        bf16* po = o + (long long)row * ldo + d0;
#pragma unroll
        for (int k = 0; k < 12; k += 4) {
            bf16x4 ov;
            ov[0] = (bf16)((xv[k]   - mu) * rs * gv[k]   + ev[k]);
            ov[1] = (bf16)((xv[k+1] - mu) * rs * gv[k+1] + ev[k+1]);
            ov[2] = (bf16)((xv[k+2] - mu) * rs * gv[k+2] + ev[k+2]);
            ov[3] = (bf16)((xv[k+3] - mu) * rs * gv[k+3] + ev[k+3]);
            *(bf16x4*)(po + k) = ov;
        }
    }
}

// ---------------------------------------------------------------------------
// LN2 fused with s-sum (wave-parallel, R10-verified).
// ---------------------------------------------------------------------------
__global__ __launch_bounds__(256)
void ln2_reduce_kernel(const bf16* __restrict__ src,  /* ffn+x1, ld 3072 */
                       const float* __restrict__ g, const float* __restrict__ be,
                       float* __restrict__ partial)
{
    const int blk  = blockIdx.x;          // 0..511 (32 rows each)
    const int tid  = threadIdx.x;
    const int wid  = tid >> 6, lane = tid & 63;
    const int d0   = lane * 12;

    float gv[12], ev[12];
#pragma unroll
    for (int k = 0; k < 12; k += 4) {
        *(float4*)(gv + k) = *(const float4*)(g + d0 + k);
        *(float4*)(ev + k) = *(const float4*)(be + d0 + k);
    }
    float acc[12];
#pragma unroll
    for (int k = 0; k < 12; ++k) acc[k] = 0.f;

    for (int i = 0; i < 8; ++i) {
        const int row = blk * 32 + i * 4 + wid;
        const bf16* p = src + (long long)row * 3072 + d0;
        float xv[12];
#pragma unroll
        for (int k = 0; k < 12; k += 4) {
            const bf16x4 v = *(const bf16x4*)(p + k);
            xv[k] = (float)v[0]; xv[k+1] = (float)v[1];
            xv[k+2] = (float)v[2]; xv[k+3] = (float)v[3];
        }
        float s1 = 0.f, s2 = 0.f;
#pragma unroll
        for (int k = 0; k < 12; ++k) { s1 += xv[k]; s2 += xv[k] * xv[k]; }
        for (int off = 32; off; off >>= 1) {
            s1 += __shfl_xor(s1, off);
            s2 += __shfl_xor(s2, off);
        }
        const float mu  = s1 * (1.0f / 768.0f);
        const float var = s2 * (1.0f / 768.0f) - mu * mu;
        const float rs  = rsqrtf(var + 1e-5f);
#pragma unroll
        for (int k = 0; k < 12; ++k) acc[k] += (xv[k] - mu) * rs * gv[k] + ev[k];
    }

    __shared__ float red[4][768];
#pragma unroll
    for (int k = 0; k < 12; k += 4)
        *(float4*)(&red[wid][d0 + k]) = *(const float4*)(acc + k);
    __syncthreads();
    if (wid == 0) {
#pragma unroll
        for (int k = 0; k < 12; k += 4) {
            const float4 a0 = *(const float4*)(&red[0][d0 + k]);
            const float4 a1 = *(const float4*)(&red[1][d0 + k]);
            const float4 a2 = *(const float4*)(&red[2][d0 + k]);
            const float4 a3 = *(const float4*)(&red[3][d0 + k]);
            *(float4*)(partial + (long long)blk * 768 + d0 + k) =
                make_float4(a0.x + a1.x + a2.x + a3.x, a0.y + a1.y + a2.y + a3.y,
                            a0.z + a1.z + a2.z + a3.z, a0.w + a1.w + a2.w + a3.w);
        }
    }
}

// stage 2
__global__ __launch_bounds__(192)
void reduce_fc2_stage2_kernel(const float* __restrict__ partial, const float* __restrict__ w,
                              const float* __restrict__ bias, float* __restrict__ out)
{
    const int b = blockIdx.x, t = threadIdx.x;
    const int d0 = t * 4;
    float a[4] = {0.f, 0.f, 0.f, 0.f};
    for (int c = 0; c < 16; ++c) {
        const float4 pv = *(const float4*)(partial + (long long)(b * 16 + c) * 768 + d0);
        a[0] += pv.x; a[1] += pv.y; a[2] += pv.z; a[3] += pv.w;
    }
    __shared__ float os[10];
    if (t < 10) os[t] = 0.f;
    __syncthreads();
    for (int c = 0; c < 10; ++c) {
        const float4 wv = *(const float4*)(w + c * 768 + d0);
        float p = wv.x * a[0] + wv.y * a[1] + wv.z * a[2] + wv.w * a[3];
        for (int off = 32; off; off >>= 1) p += __shfl_xor(p, off);
        if ((t & 63) == 0) atomicAdd(&os[c], p);
    }
    __syncthreads();
    if (t < 10) out[b * 10 + t] = os[t] + bias[t];
}

// ---------------------------------------------------------------------------
// workspace layout (bytes)
// ---------------------------------------------------------------------------
static const size_t OFF_XPE  = 0;
static const size_t OFF_WCAT = OFF_XPE  + (size_t)16384 * 768 * 2;
static const size_t OFF_WT3  = OFF_WCAT + (size_t)3072 * 768 * 2;
static const size_t OFF_INPJ = OFF_WT3  + (size_t)3 * 768 * 768 * 2;
static const size_t OFF_WOUT = OFF_INPJ + (size_t)2304 * 768 * 2;
static const size_t OFF_WF1A = OFF_WOUT + (size_t)768 * 768 * 2;
static const size_t OFF_WF1B = OFF_WF1A + (size_t)768 * 768 * 2;
static const size_t OFF_BCAT = OFF_WF1B + (size_t)768 * 768 * 2;
static const size_t OFF_QKVX = OFF_BCAT + (size_t)3072 * 4;
static const size_t OFF_VT   = OFF_QKVX + (size_t)16384 * 3072 * 2;   // R24: PETAB here
static const size_t OFF_S    = OFF_VT   + (size_t)128 * 192 * 512 * 2; // fc2 partials
static const size_t OFF_X1   = OFF_S    + (size_t)128 * 512 * 512 * 2;

extern "C" void kernel_launch(void* const* d_in, const int* in_sizes, int n_in,
                              void* d_out, int out_size, void* d_ws, size_t ws_size,
                              hipStream_t stream)
{
    const float* x     = (const float*)d_in[0];
    const float* wq    = (const float*)d_in[1];
    const float* bq    = (const float*)d_in[2];
    const float* wk    = (const float*)d_in[3];
    const float* bk    = (const float*)d_in[4];
    const float* wv    = (const float*)d_in[5];
    const float* bv    = (const float*)d_in[6];
    const float* wx    = (const float*)d_in[7];
    const float* bx    = (const float*)d_in[8];
    const float* inpw  = (const float*)d_in[9];
    const float* inpb  = (const float*)d_in[10];
    const float* woutp = (const float*)d_in[11];
    const float* boutp = (const float*)d_in[12];
    const float* wf1a  = (const float*)d_in[13];
    const float* bf1a  = (const float*)d_in[14];
    const float* wf1b  = (const float*)d_in[15];
    const float* bf1b  = (const float*)d_in[16];
    const float* lng   = (const float*)d_in[17];
    const float* lnb   = (const float*)d_in[18];
    const float* wfc2  = (const float*)d_in[19];
    const float* bfc2  = (const float*)d_in[20];
    float* out = (float*)d_out;

    char* ws = (char*)d_ws;
    bf16*  XPE  = (bf16*)(ws + OFF_XPE);
    bf16*  WCAT = (bf16*)(ws + OFF_WCAT);
    bf16*  WT3  = (bf16*)(ws + OFF_WT3);
    bf16*  INPJ = (bf16*)(ws + OFF_INPJ);
    bf16*  WOUT = (bf16*)(ws + OFF_WOUT);
    bf16*  WF1A = (bf16*)(ws + OFF_WF1A);
    bf16*  WF1B = (bf16*)(ws + OFF_WF1B);
    float* BCAT = (float*)(ws + OFF_BCAT);
    bf16*  QKVX = (bf16*)(ws + OFF_QKVX);
    float* PETB = (float*)(ws + OFF_VT);
    float* PART = (float*)(ws + OFF_S);
    bf16*  X1   = (bf16*)(ws + OFF_X1);

    // ---- R24: PE table (512x768 floats, computed once) ----
    pe_kernel<<<384, 256, 0, stream>>>(PETB);

    // ---- prep: weights + bias + x+PE (single dispatch, trig-free) ----
    prep_kernel<<<18339, 256, 0, stream>>>(wq, wk, wv, wx, inpw, inpb,
                                           bq, bk, bv, bx, woutp, wf1a, wf1b, x,
                                           WT3, INPJ, WOUT, WF1A, WF1B,
                                           WCAT + (size_t)2304 * 768, BCAT, XPE,
                                           PETB);

    // W_eff[z] = in_proj_w[z] @ w{q,k,v}
    gemm_nt<64, 128, 2, 4><<<dim3(6, 12, 3), 256, 0, stream>>>(
        INPJ, WT3, WCAT, nullptr, 768, 768, 768, 768,
        1, 589824, 0, 589824, 0, 589824, 0, 1.0f, 0, nullptr, 0);

    // QKVX = XPE @ WCAT^T + BCAT -> [16384,3072]  (R15 fenced flow, 926 TF)
    gemm_qkv_8ph<<<dim3(12, 64, 1), 512, 0, stream>>>(XPE, WCAT, QKVX, BCAT);

    // fused attention (R18 version):
    // Q2 region overwritten with ctx
    fused_attn_kernel<<<512, 256, 0, stream>>>(QKVX);

    // attn_out + XR residual -> K2 region  (flow, swapped grid)
    gemm_flow<<<dim3(64, 4, 1), 512, 0, stream>>>(
        QKVX, WOUT, QKVX + 768, boutp, 3072, 768, 3072,
        0, QKVX + 2304, 3072);

    // x1 = LN(attn_out + XR)  (R19: 32 rows/block)
    ln1_kernel<<<512, 256, 0, stream>>>(QKVX + 768, 3072, X1, 768, lng, lnb);

    // h1 = relu(x1 @ fc1a^T + b) -> V2 region
    gemm_flow<<<dim3(64, 4, 1), 512, 0, stream>>>(
        X1, WF1A, QKVX + 1536, bf1a, 768, 768, 3072,
        1, nullptr, 0);

    // ffn + x1 residual -> XR region
    gemm_flow<<<dim3(64, 4, 1), 512, 0, stream>>>(
        QKVX + 1536, WF1B, QKVX + 2304, bf1b, 3072, 768, 3072,
        0, X1, 768);

    // LN2 + s-sum fused (x2 never materialized)
    ln2_reduce_kernel<<<512, 256, 0, stream>>>(QKVX + 2304, lng, lnb, PART);

    // out = partial-sum @ fc2^T + b
    reduce_fc2_stage2_kernel<<<32, 192, 0, stream>>>(PART, wfc2, bfc2, out);
}